// Round 1
// baseline (560.889 us; speedup 1.0000x reference)
//
#include <hip/hip_runtime.h>
#include <hip/hip_bf16.h>
#include <math.h>

#define B_ 16
#define NT 64
#define LN 256
#define LV 4
#define D_ 256
#define VOCAB_ 32000
#define M_ 128
#define LS 4

// ---------------- K1: roots[b,n,d] = sum_l T_emb[type] * sum_j C0[val_j] ----
__global__ __launch_bounds__(256) void k_roots(
    const int* __restrict__ kb_values, const int* __restrict__ kb_types,
    const float* __restrict__ C0, const float* __restrict__ T_emb,
    float* __restrict__ roots, float* __restrict__ bias) {
  int bn = blockIdx.x;   // 0..1023
  int d  = threadIdx.x;  // 0..255
  __shared__ int sv[LN * LV];
  __shared__ int st[LN];
  const int* vptr = kb_values + (size_t)bn * LN * LV;
  for (int i = d; i < LN * LV; i += 256) sv[i] = vptr[i];
  st[d] = kb_types[(size_t)bn * LN + d];
  __syncthreads();
  float acc = 0.f;
#pragma unroll 4
  for (int l = 0; l < LN; ++l) {
    const int* v = &sv[l * LV];
    float s = C0[(size_t)v[0] * D_ + d] + C0[(size_t)v[1] * D_ + d] +
              C0[(size_t)v[2] * D_ + d] + C0[(size_t)v[3] * D_ + d];
    acc += T_emb[st[l] * D_ + d] * s;
  }
  roots[(size_t)bn * D_ + d] = acc;
  // block-reduce for the (sum==0 -> -1e9) bias
  __shared__ float red[256];
  red[d] = acc;
  __syncthreads();
  for (int s = 128; s > 0; s >>= 1) {
    if (d < s) red[d] += red[d + s];
    __syncthreads();
  }
  if (d == 0) bias[bn] = (red[0] == 0.0f) ? -1000000000.0f : 0.0f;
}

// ---------------- K2: t[b,:] = (h @ Wq^T) @ Wk ------------------------------
__global__ __launch_bounds__(256) void k_t(
    const float* __restrict__ hidden, const float* __restrict__ Wq,
    const float* __restrict__ Wk, float* __restrict__ tvec) {
  int b = blockIdx.x, i = threadIdx.x;
  __shared__ float hs[D_], qs[D_];
  hs[i] = hidden[b * D_ + i];
  __syncthreads();
  float q = 0.f;
  const float* wq = Wq + (size_t)i * D_;
#pragma unroll 4
  for (int j = 0; j < D_; ++j) q += hs[j] * wq[j];
  qs[i] = q;
  __syncthreads();
  float t = 0.f;
#pragma unroll 4
  for (int k = 0; k < D_; ++k) t += Wk[(size_t)k * D_ + i] * qs[k];
  tvec[b * D_ + i] = t;
}

// ---------------- K3: softmax(roots.t + bias) -> rbar -----------------------
__global__ __launch_bounds__(256) void k_attn(
    const float* __restrict__ roots, const float* __restrict__ bias,
    const float* __restrict__ tvec, float* __restrict__ rbar) {
  int b = blockIdx.x, tid = threadIdx.x;
  __shared__ float ts[D_], wsh[NT];
  ts[tid] = tvec[b * D_ + tid];
  __syncthreads();
  if (tid < NT) {
    const float* r = roots + ((size_t)b * NT + tid) * D_;
    float s = 0.f;
#pragma unroll 4
    for (int dd = 0; dd < D_; ++dd) s += r[dd] * ts[dd];
    s += bias[b * NT + tid];
    float m = s;
    for (int o = 32; o > 0; o >>= 1) m = fmaxf(m, __shfl_xor(m, o));
    float e = expf(s - m);
    float sum = e;
    for (int o = 32; o > 0; o >>= 1) sum += __shfl_xor(sum, o);
    wsh[tid] = e / sum;
  }
  __syncthreads();
  float acc = 0.f;
#pragma unroll 4
  for (int n = 0; n < NT; ++n)
    acc += wsh[n] * roots[((size_t)b * NT + n) * D_ + tid];
  rbar[b * D_ + tid] = acc;
}

// ---------------- K4: feat = rbar@Wv^T ; GRU ; write h_new, u0 --------------
__global__ __launch_bounds__(256) void k_gru(
    const float* __restrict__ rbar, const float* __restrict__ Wv,
    const int* __restrict__ dec, const float* __restrict__ C0,
    const float* __restrict__ hidden, const float* __restrict__ W_ih,
    const float* __restrict__ W_hh, const float* __restrict__ b_ih,
    const float* __restrict__ b_hh, float* __restrict__ h_new_out,
    float* __restrict__ cat) {
  int b = blockIdx.x, tid = threadIdx.x;
  __shared__ float rs[D_], hs[D_], xs[D_];
  rs[tid] = rbar[b * D_ + tid];
  hs[tid] = hidden[b * D_ + tid];
  xs[tid] = C0[(size_t)dec[b] * D_ + tid];
  __syncthreads();
  float feat = 0.f;
  const float* wv = Wv + (size_t)tid * D_;
#pragma unroll 4
  for (int j = 0; j < D_; ++j) feat += rs[j] * wv[j];
  float gi[3], gh[3];
  for (int g = 0; g < 3; ++g) {
    const float* wi = W_ih + (size_t)(g * D_ + tid) * D_;
    const float* wh = W_hh + (size_t)(g * D_ + tid) * D_;
    float a = b_ih[g * D_ + tid], c = b_hh[g * D_ + tid];
#pragma unroll 4
    for (int j = 0; j < D_; ++j) {
      a += xs[j] * wi[j];
      c += hs[j] * wh[j];
    }
    gi[g] = a;
    gh[g] = c;
  }
  float r = 1.f / (1.f + expf(-(gi[0] + gh[0])));
  float z = 1.f / (1.f + expf(-(gi[1] + gh[1])));
  float nn = tanhf(gi[2] + r * gh[2]);
  float hn = (1.f - z) * nn + z * hs[tid];
  h_new_out[b * D_ + tid] = hn;
  cat[b * 512 + tid] = hn + feat;  // u0
}

// ---------------- K5: S[h][b,m,:] = sum_j C[h][story[b,m,j]] ---------------
__global__ __launch_bounds__(256) void k_S(
    const int* __restrict__ story, const float* __restrict__ C,
    float* __restrict__ S) {
  int idx = blockIdx.x;  // h*B*M + b*M + m, h in 0..2
  int h = idx / (B_ * M_);
  int bm = idx % (B_ * M_);
  int d = threadIdx.x;
  const int* st = story + (size_t)bm * LS;
  const float* Ch = C + (size_t)h * VOCAB_ * D_;
  float s = Ch[(size_t)st[0] * D_ + d] + Ch[(size_t)st[1] * D_ + d] +
            Ch[(size_t)st[2] * D_ + d] + Ch[(size_t)st[3] * D_ + d];
  S[(size_t)idx * D_ + d] = s;
}

// ---------------- K6: hop chain; writes p_ptr, o0 into cat ------------------
__global__ __launch_bounds__(256) void k_hops(
    const float* __restrict__ S, float* __restrict__ cat,
    float* __restrict__ p_ptr) {
  int b = blockIdx.x, tid = threadIdx.x;
  __shared__ float us[D_], lo[M_], pr[M_];
  us[tid] = cat[b * 512 + tid];  // u0
  __syncthreads();
  for (int h = 0; h < 3; ++h) {
    if (tid < M_) {
      const float* sr = S + (((size_t)h * B_ + b) * M_ + tid) * D_;
      float l = 0.f;
#pragma unroll 4
      for (int dd = 0; dd < D_; ++dd) l += sr[dd] * us[dd];
      lo[tid] = l;
      if (h == 2) p_ptr[b * M_ + tid] = l;
    }
    __syncthreads();
    if (h == 2) break;
    if (tid < 64) {
      float a = fmaxf(lo[tid], lo[tid + 64]);
      for (int o = 32; o > 0; o >>= 1) a = fmaxf(a, __shfl_xor(a, o));
      float e0 = expf(lo[tid] - a), e1 = expf(lo[tid + 64] - a);
      float s = e0 + e1;
      for (int o = 32; o > 0; o >>= 1) s += __shfl_xor(s, o);
      pr[tid] = e0 / s;
      pr[tid + 64] = e1 / s;
    }
    __syncthreads();
    const float* Sn = S + (((size_t)(h + 1) * B_ + b) * M_) * D_;
    float o = 0.f;
#pragma unroll 4
    for (int m = 0; m < M_; ++m) o += pr[m] * Sn[(size_t)m * D_ + tid];
    if (h == 0) cat[b * 512 + 256 + tid] = o;  // o0
    us[tid] += o;
    __syncthreads();
  }
}

// ---------------- K7: p_vocab = cat @ W1_w^T + b ----------------------------
__global__ __launch_bounds__(128) void k_pvocab(
    const float* __restrict__ cat, const float* __restrict__ W1_w,
    const float* __restrict__ W1_b, float* __restrict__ out) {
  int v = blockIdx.x * 128 + threadIdx.x;
  __shared__ float cs[B_ * 512];
  for (int i = threadIdx.x; i < B_ * 512; i += 128) cs[i] = cat[i];
  __syncthreads();
  const float4* wrow = (const float4*)(W1_w + (size_t)v * 512);
  float acc[B_];
#pragma unroll
  for (int b = 0; b < B_; ++b) acc[b] = 0.f;
  for (int k4 = 0; k4 < 128; ++k4) {
    float4 w = wrow[k4];
#pragma unroll
    for (int b = 0; b < B_; ++b) {
      const float* c = &cs[b * 512 + k4 * 4];
      acc[b] += w.x * c[0] + w.y * c[1] + w.z * c[2] + w.w * c[3];
    }
  }
  float bb = W1_b[v];
#pragma unroll
  for (int b = 0; b < B_; ++b) out[(size_t)b * VOCAB_ + v] = acc[b] + bb;
}

extern "C" void kernel_launch(void* const* d_in, const int* in_sizes, int n_in,
                              void* d_out, int out_size, void* d_ws,
                              size_t ws_size, hipStream_t stream) {
  const int* decoder_input = (const int*)d_in[0];
  const int* story = (const int*)d_in[1];
  const float* hidden = (const float*)d_in[2];
  const int* kb_values = (const int*)d_in[3];
  const int* kb_types = (const int*)d_in[4];
  // d_in[5] kb_fathers, d_in[6] kb_n_layers: not needed (roots = total sum)
  const float* C = (const float*)d_in[7];
  const float* T_emb = (const float*)d_in[8];
  const float* Wq = (const float*)d_in[9];
  const float* Wk = (const float*)d_in[10];
  const float* Wv = (const float*)d_in[11];
  const float* W1_w = (const float*)d_in[12];
  const float* W1_b = (const float*)d_in[13];
  const float* W_ih = (const float*)d_in[14];
  const float* W_hh = (const float*)d_in[15];
  const float* b_ih = (const float*)d_in[16];
  const float* b_hh = (const float*)d_in[17];

  float* out = (float*)d_out;
  float* p_ptr = out;                       // (16,128)
  float* p_vocab = out + B_ * M_;           // (16,32000)
  float* h_new = out + B_ * M_ + B_ * VOCAB_;  // (16,256)

  // workspace layout (floats)
  float* ws = (float*)d_ws;
  float* roots = ws;                     // 262144
  float* bias = roots + B_ * NT * D_;    // 1024
  float* tvec = bias + B_ * NT;          // 4096
  float* rbar = tvec + B_ * D_;          // 4096
  float* cat = rbar + B_ * D_;           // 8192 (u0|o0)
  float* S = cat + B_ * 512;             // 3*16*128*256 = 1572864

  hipLaunchKernelGGL(k_roots, dim3(B_ * NT), dim3(256), 0, stream, kb_values,
                     kb_types, C, T_emb, roots, bias);
  hipLaunchKernelGGL(k_S, dim3(3 * B_ * M_), dim3(256), 0, stream, story, C, S);
  hipLaunchKernelGGL(k_t, dim3(B_), dim3(256), 0, stream, hidden, Wq, Wk, tvec);
  hipLaunchKernelGGL(k_attn, dim3(B_), dim3(256), 0, stream, roots, bias, tvec,
                     rbar);
  hipLaunchKernelGGL(k_gru, dim3(B_), dim3(256), 0, stream, rbar, Wv,
                     decoder_input, C, hidden, W_ih, W_hh, b_ih, b_hh, h_new,
                     cat);
  hipLaunchKernelGGL(k_hops, dim3(B_), dim3(256), 0, stream, S, cat, p_ptr);
  hipLaunchKernelGGL(k_pvocab, dim3(VOCAB_ / 128), dim3(128), 0, stream, cat,
                     W1_w, W1_b, p_vocab);
}

// Round 2
// 498.945 us; speedup vs baseline: 1.1241x; 1.1241x over previous
//
#include <hip/hip_runtime.h>
#include <hip/hip_bf16.h>
#include <math.h>

#define B_ 16
#define NT 64
#define LN 256
#define LV 4
#define D_ 256
#define VOCAB_ 32000
#define M_ 128
#define LS 4

typedef unsigned short ushort_t;
typedef unsigned int uint_t;

__device__ __forceinline__ ushort_t f2bf(float f) {
  uint_t u = __float_as_uint(f);
  uint_t r = u + 0x7FFFu + ((u >> 16) & 1u);  // round-to-nearest-even
  return (ushort_t)(r >> 16);
}
__device__ __forceinline__ float bf2f(ushort_t h) {
  return __uint_as_float(((uint_t)h) << 16);
}

// ---------------- K0: convert C0 (VOCAB x D fp32) -> bf16 table -------------
__global__ __launch_bounds__(256) void k_conv(const float* __restrict__ C0,
                                              ushort_t* __restrict__ C0h) {
  int n4 = VOCAB_ * D_ / 4;  // 2,048,000
  for (int i = blockIdx.x * 256 + threadIdx.x; i < n4; i += gridDim.x * 256) {
    float4 f = ((const float4*)C0)[i];
    ushort_t h0 = f2bf(f.x), h1 = f2bf(f.y), h2 = f2bf(f.z), h3 = f2bf(f.w);
    uint2 packed;
    packed.x = (uint_t)h0 | ((uint_t)h1 << 16);
    packed.y = (uint_t)h2 | ((uint_t)h3 << 16);
    ((uint2*)C0h)[i] = packed;
  }
}

// ---------------- K1: partial roots; 2 blocks per (b,n), 128 leaves each ----
__global__ __launch_bounds__(256) void k_roots(
    const int* __restrict__ kb_values, const int* __restrict__ kb_types,
    const ushort_t* __restrict__ C0h, const float* __restrict__ T_emb,
    float* __restrict__ part) {
  int blk = blockIdx.x;        // 0..2047
  int bn = blk >> 1;
  int half = blk & 1;
  int d = threadIdx.x;         // 0..255
  __shared__ int sv[128 * LV];
  __shared__ int st[128];
  const int* vptr = kb_values + (size_t)bn * LN * LV + half * 128 * LV;
  for (int i = d; i < 128 * LV; i += 256) sv[i] = vptr[i];
  if (d < 128) st[d] = kb_types[(size_t)bn * LN + half * 128 + d];
  __syncthreads();
  float acc = 0.f;
#pragma unroll 2
  for (int l = 0; l < 128; ++l) {
    const int* v = &sv[l * LV];
    float s = bf2f(C0h[(size_t)v[0] * D_ + d]) +
              bf2f(C0h[(size_t)v[1] * D_ + d]) +
              bf2f(C0h[(size_t)v[2] * D_ + d]) +
              bf2f(C0h[(size_t)v[3] * D_ + d]);
    acc += T_emb[st[l] * D_ + d] * s;
  }
  part[((size_t)bn * 2 + half) * D_ + d] = acc;
}

// ---------------- K2: S[h][b,m,:] = sum_j C[h][story[b,m,j]] ---------------
__global__ __launch_bounds__(256) void k_S(
    const int* __restrict__ story, const float* __restrict__ C,
    float* __restrict__ S) {
  int idx = blockIdx.x;  // h*B*M + b*M + m, h in 0..2
  int h = idx / (B_ * M_);
  int bm = idx % (B_ * M_);
  int d = threadIdx.x;
  const int* st = story + (size_t)bm * LS;
  const float* Ch = C + (size_t)h * VOCAB_ * D_;
  float s = Ch[(size_t)st[0] * D_ + d] + Ch[(size_t)st[1] * D_ + d] +
            Ch[(size_t)st[2] * D_ + d] + Ch[(size_t)st[3] * D_ + d];
  S[(size_t)idx * D_ + d] = s;
}

// ---------------- K3: fused t / attention / GRU / hops ----------------------
__global__ __launch_bounds__(256) void k_seq(
    const float* __restrict__ part, const float* __restrict__ hidden,
    const float* __restrict__ Wq, const float* __restrict__ Wk,
    const float* __restrict__ Wv, const int* __restrict__ dec,
    const float* __restrict__ C0, const float* __restrict__ W_ih,
    const float* __restrict__ W_hh, const float* __restrict__ b_ih,
    const float* __restrict__ b_hh, const float* __restrict__ S,
    float* __restrict__ h_new_out, float* __restrict__ cat,
    float* __restrict__ p_ptr) {
  int b = blockIdx.x, tid = threadIdx.x;
  __shared__ float hs[D_], qs[D_], ts[D_], xs[D_], rs[D_], us[D_];
  __shared__ float wsh[NT], lo[M_], pr[M_];
  hs[tid] = hidden[b * D_ + tid];
  xs[tid] = C0[(size_t)dec[b] * D_ + tid];
  __syncthreads();
  // q = h @ Wq^T
  {
    float q = 0.f;
    const float* wq = Wq + (size_t)tid * D_;
#pragma unroll 4
    for (int j = 0; j < D_; ++j) q += hs[j] * wq[j];
    qs[tid] = q;
  }
  __syncthreads();
  // t = q @ Wk  (t_i = sum_k Wk[k,i] q[k])
  {
    float t = 0.f;
#pragma unroll 4
    for (int k = 0; k < D_; ++k) t += Wk[(size_t)k * D_ + tid] * qs[k];
    ts[tid] = t;
  }
  __syncthreads();
  // attention over 64 roots (wave 0)
  if (tid < NT) {
    const float* r0 = part + ((size_t)b * NT + tid) * (2 * D_);
    const float* r1 = r0 + D_;
    float s = 0.f, ssum = 0.f;
#pragma unroll 4
    for (int dd = 0; dd < D_; ++dd) {
      float rv = r0[dd] + r1[dd];
      s += rv * ts[dd];
      ssum += rv;
    }
    if (ssum == 0.0f) s -= 1000000000.0f;
    float m = s;
    for (int o = 32; o > 0; o >>= 1) m = fmaxf(m, __shfl_xor(m, o));
    float e = expf(s - m);
    float sum = e;
    for (int o = 32; o > 0; o >>= 1) sum += __shfl_xor(sum, o);
    wsh[tid] = e / sum;
  }
  __syncthreads();
  // rbar
  {
    float rb = 0.f;
#pragma unroll 4
    for (int n = 0; n < NT; ++n) {
      const float* p = part + ((size_t)b * NT + n) * (2 * D_);
      rb += wsh[n] * (p[tid] + p[D_ + tid]);
    }
    rs[tid] = rb;
  }
  __syncthreads();
  // feat = rbar @ Wv^T ; GRU
  float feat = 0.f;
  {
    const float* wv = Wv + (size_t)tid * D_;
#pragma unroll 4
    for (int j = 0; j < D_; ++j) feat += rs[j] * wv[j];
  }
  float gi[3], gh[3];
  for (int g = 0; g < 3; ++g) {
    const float* wi = W_ih + (size_t)(g * D_ + tid) * D_;
    const float* wh = W_hh + (size_t)(g * D_ + tid) * D_;
    float a = b_ih[g * D_ + tid], c = b_hh[g * D_ + tid];
#pragma unroll 4
    for (int j = 0; j < D_; ++j) {
      a += xs[j] * wi[j];
      c += hs[j] * wh[j];
    }
    gi[g] = a;
    gh[g] = c;
  }
  {
    float r = 1.f / (1.f + expf(-(gi[0] + gh[0])));
    float z = 1.f / (1.f + expf(-(gi[1] + gh[1])));
    float nn = tanhf(gi[2] + r * gh[2]);
    float hn = (1.f - z) * nn + z * hs[tid];
    h_new_out[b * D_ + tid] = hn;
    float u0 = hn + feat;
    us[tid] = u0;
    cat[b * 512 + tid] = u0;
  }
  __syncthreads();
  // hops
  for (int h = 0; h < 3; ++h) {
    if (tid < M_) {
      const float* sr = S + (((size_t)h * B_ + b) * M_ + tid) * D_;
      float l = 0.f;
#pragma unroll 4
      for (int dd = 0; dd < D_; ++dd) l += sr[dd] * us[dd];
      lo[tid] = l;
      if (h == 2) p_ptr[b * M_ + tid] = l;
    }
    __syncthreads();
    if (h == 2) break;
    if (tid < 64) {
      float a = fmaxf(lo[tid], lo[tid + 64]);
      for (int o = 32; o > 0; o >>= 1) a = fmaxf(a, __shfl_xor(a, o));
      float e0 = expf(lo[tid] - a), e1 = expf(lo[tid + 64] - a);
      float s = e0 + e1;
      for (int o = 32; o > 0; o >>= 1) s += __shfl_xor(s, o);
      pr[tid] = e0 / s;
      pr[tid + 64] = e1 / s;
    }
    __syncthreads();
    const float* Sn = S + (((size_t)(h + 1) * B_ + b) * M_) * D_;
    float o = 0.f;
#pragma unroll 4
    for (int m = 0; m < M_; ++m) o += pr[m] * Sn[(size_t)m * D_ + tid];
    if (h == 0) cat[b * 512 + D_ + tid] = o;
    us[tid] += o;
    __syncthreads();
  }
}

// ---------------- K4: p_vocab = cat @ W1_w^T + b ----------------------------
__global__ __launch_bounds__(128) void k_pvocab(
    const float* __restrict__ cat, const float* __restrict__ W1_w,
    const float* __restrict__ W1_b, float* __restrict__ out) {
  int v = blockIdx.x * 128 + threadIdx.x;
  __shared__ float cs[B_ * 512];
  for (int i = threadIdx.x; i < B_ * 512; i += 128) cs[i] = cat[i];
  __syncthreads();
  const float4* wrow = (const float4*)(W1_w + (size_t)v * 512);
  float acc[B_];
#pragma unroll
  for (int b = 0; b < B_; ++b) acc[b] = 0.f;
  for (int k4 = 0; k4 < 128; ++k4) {
    float4 w = wrow[k4];
#pragma unroll
    for (int b = 0; b < B_; ++b) {
      const float* c = &cs[b * 512 + k4 * 4];
      acc[b] += w.x * c[0] + w.y * c[1] + w.z * c[2] + w.w * c[3];
    }
  }
  float bb = W1_b[v];
#pragma unroll
  for (int b = 0; b < B_; ++b) out[(size_t)b * VOCAB_ + v] = acc[b] + bb;
}

extern "C" void kernel_launch(void* const* d_in, const int* in_sizes, int n_in,
                              void* d_out, int out_size, void* d_ws,
                              size_t ws_size, hipStream_t stream) {
  const int* decoder_input = (const int*)d_in[0];
  const int* story = (const int*)d_in[1];
  const float* hidden = (const float*)d_in[2];
  const int* kb_values = (const int*)d_in[3];
  const int* kb_types = (const int*)d_in[4];
  // d_in[5] kb_fathers, d_in[6] kb_n_layers: not needed (roots = total sum)
  const float* C = (const float*)d_in[7];
  const float* T_emb = (const float*)d_in[8];
  const float* Wq = (const float*)d_in[9];
  const float* Wk = (const float*)d_in[10];
  const float* Wv = (const float*)d_in[11];
  const float* W1_w = (const float*)d_in[12];
  const float* W1_b = (const float*)d_in[13];
  const float* W_ih = (const float*)d_in[14];
  const float* W_hh = (const float*)d_in[15];
  const float* b_ih = (const float*)d_in[16];
  const float* b_hh = (const float*)d_in[17];

  float* out = (float*)d_out;
  float* p_ptr = out;                          // (16,128)
  float* p_vocab = out + B_ * M_;              // (16,32000)
  float* h_new = out + B_ * M_ + B_ * VOCAB_;  // (16,256)

  // workspace layout
  float* ws = (float*)d_ws;
  float* S = ws;                               // 1,572,864 floats
  float* part = S + 3 * B_ * M_ * D_;          //   524,288 floats
  float* cat = part + B_ * NT * 2 * D_;        //     8,192 floats
  ushort_t* C0h = (ushort_t*)(cat + B_ * 512); // 8,192,000 ushorts (16 MB)

  hipLaunchKernelGGL(k_conv, dim3(2048), dim3(256), 0, stream, C, C0h);
  hipLaunchKernelGGL(k_roots, dim3(2 * B_ * NT), dim3(256), 0, stream,
                     kb_values, kb_types, C0h, T_emb, part);
  hipLaunchKernelGGL(k_S, dim3(3 * B_ * M_), dim3(256), 0, stream, story, C, S);
  hipLaunchKernelGGL(k_seq, dim3(B_), dim3(256), 0, stream, part, hidden, Wq,
                     Wk, Wv, decoder_input, C, W_ih, W_hh, b_ih, b_hh, S, h_new,
                     cat, p_ptr);
  hipLaunchKernelGGL(k_pvocab, dim3(VOCAB_ / 128), dim3(128), 0, stream, cat,
                     W1_w, W1_b, p_vocab);
}

// Round 3
// 480.186 us; speedup vs baseline: 1.1681x; 1.0391x over previous
//
#include <hip/hip_runtime.h>
#include <hip/hip_bf16.h>
#include <math.h>

#define B_ 16
#define NT 64
#define LN 256
#define LV 4
#define D_ 256
#define VOCAB_ 32000
#define M_ 128
#define LS 4

typedef unsigned short ushort_t;
typedef unsigned int uint_t;

__device__ __forceinline__ ushort_t f2bf(float f) {
  uint_t u = __float_as_uint(f);
  uint_t r = u + 0x7FFFu + ((u >> 16) & 1u);
  return (ushort_t)(r >> 16);
}
__device__ __forceinline__ float bf2f(ushort_t h) {
  return __uint_as_float(((uint_t)h) << 16);
}

// ---------------- K_prep: S gather | C0->bf16 | W_ih^T | W_hh^T | TQK -------
// roles by blockIdx: [0,6144) S; [6144,8192) conv; [8192,8384) W_ihT;
// [8384,8576) W_hhT; [8576,8832) TQK
#define NB_S (3 * B_ * M_)      // 6144
#define NB_CONV 2048
#define NB_TR 192               // 768x256 -> 24x8 tiles of 32x32
__global__ __launch_bounds__(256) void k_prep(
    const int* __restrict__ story, const float* __restrict__ C,
    const float* __restrict__ W_ih, const float* __restrict__ W_hh,
    const float* __restrict__ Wq, const float* __restrict__ Wk,
    float* __restrict__ S, ushort_t* __restrict__ C0h,
    float* __restrict__ W_ihT, float* __restrict__ W_hhT,
    float* __restrict__ TQK) {
  __shared__ float smem[32 * 33];
  int blk = blockIdx.x, tid = threadIdx.x;
  if (blk < NB_S) {
    int h = blk / (B_ * M_);
    int bm = blk % (B_ * M_);
    const int* st = story + (size_t)bm * LS;
    const float* Ch = C + (size_t)h * VOCAB_ * D_;
    float s = Ch[(size_t)st[0] * D_ + tid] + Ch[(size_t)st[1] * D_ + tid] +
              Ch[(size_t)st[2] * D_ + tid] + Ch[(size_t)st[3] * D_ + tid];
    S[(size_t)blk * D_ + tid] = s;
  } else if (blk < NB_S + NB_CONV) {
    int n4 = VOCAB_ * D_ / 4;
    for (int i = (blk - NB_S) * 256 + tid; i < n4; i += NB_CONV * 256) {
      float4 f = ((const float4*)C)[i];
      uint2 packed;
      packed.x = (uint_t)f2bf(f.x) | ((uint_t)f2bf(f.y) << 16);
      packed.y = (uint_t)f2bf(f.z) | ((uint_t)f2bf(f.w) << 16);
      ((uint2*)C0h)[i] = packed;
    }
  } else if (blk < NB_S + NB_CONV + 2 * NB_TR) {
    int t = blk - (NB_S + NB_CONV);
    const float* W = W_ih;
    float* WT = W_ihT;
    if (t >= NB_TR) { t -= NB_TR; W = W_hh; WT = W_hhT; }
    const int R = 768, Cc = 256;
    int tr = t % (R / 32), tc = t / (R / 32);
    int tx = tid & 31, ty = tid >> 5;  // 8 rows per pass
#pragma unroll
    for (int k = 0; k < 4; ++k)
      smem[(ty + 8 * k) * 33 + tx] =
          W[(size_t)(tr * 32 + ty + 8 * k) * Cc + tc * 32 + tx];
    __syncthreads();
#pragma unroll
    for (int k = 0; k < 4; ++k)
      WT[(size_t)(tc * 32 + ty + 8 * k) * R + tr * 32 + tx] =
          smem[tx * 33 + ty + 8 * k];
  } else {
    // TQK[j,i] = sum_k Wq[k,j] * Wk[k,i]
    int j = blk - (NB_S + NB_CONV + 2 * NB_TR);
    smem[tid] = Wq[(size_t)tid * D_ + j];
    __syncthreads();
    float acc = 0.f;
#pragma unroll 8
    for (int k = 0; k < D_; ++k) acc += smem[k] * Wk[(size_t)k * D_ + tid];
    TQK[(size_t)j * D_ + tid] = acc;
  }
}

// ---------------- K_roots: partial roots, 2 blocks per (b,n) ----------------
__global__ __launch_bounds__(256) void k_roots(
    const int* __restrict__ kb_values, const int* __restrict__ kb_types,
    const ushort_t* __restrict__ C0h, const float* __restrict__ T_emb,
    float* __restrict__ part) {
  int blk = blockIdx.x;  // 0..2047
  int bn = blk >> 1;
  int half = blk & 1;
  int d = threadIdx.x;
  __shared__ int sv[128 * LV];
  __shared__ int st[128];
  const int* vptr = kb_values + (size_t)bn * LN * LV + half * 128 * LV;
  for (int i = d; i < 128 * LV; i += 256) sv[i] = vptr[i];
  if (d < 128) st[d] = kb_types[(size_t)bn * LN + half * 128 + d];
  __syncthreads();
  float acc = 0.f;
#pragma unroll 2
  for (int l = 0; l < 128; ++l) {
    const int* v = &sv[l * LV];
    float s = bf2f(C0h[(size_t)v[0] * D_ + d]) +
              bf2f(C0h[(size_t)v[1] * D_ + d]) +
              bf2f(C0h[(size_t)v[2] * D_ + d]) +
              bf2f(C0h[(size_t)v[3] * D_ + d]);
    acc += T_emb[st[l] * D_ + d] * s;
  }
  part[((size_t)bn * 2 + half) * D_ + d] = acc;
}

// ---------------- K_gates: gi, gh (768 each), t (256), B=16 in registers ----
// blk 0..2: gi   blk 3..5: gh   blk 6: t
__global__ __launch_bounds__(256) void k_gates(
    const int* __restrict__ dec, const float* __restrict__ C0,
    const float* __restrict__ hidden, const float* __restrict__ W_ihT,
    const float* __restrict__ W_hhT, const float* __restrict__ TQK,
    const float* __restrict__ b_ih, const float* __restrict__ b_hh,
    float* __restrict__ gi, float* __restrict__ gh, float* __restrict__ tvec) {
  int blk = blockIdx.x, tid = threadIdx.x;
  __shared__ float xs[B_][D_];
  float acc[B_];
  if (blk < 3) {
#pragma unroll
    for (int b = 0; b < B_; ++b) xs[b][tid] = C0[(size_t)dec[b] * D_ + tid];
    __syncthreads();
    int i = blk * 256 + tid;
    float bias = b_ih[i];
#pragma unroll
    for (int b = 0; b < B_; ++b) acc[b] = bias;
#pragma unroll 4
    for (int j = 0; j < D_; ++j) {
      float w = W_ihT[(size_t)j * 768 + i];
#pragma unroll
      for (int b = 0; b < B_; ++b) acc[b] += xs[b][j] * w;
    }
#pragma unroll
    for (int b = 0; b < B_; ++b) gi[(size_t)b * 768 + i] = acc[b];
  } else if (blk < 6) {
#pragma unroll
    for (int b = 0; b < B_; ++b) xs[b][tid] = hidden[b * D_ + tid];
    __syncthreads();
    int i = (blk - 3) * 256 + tid;
    float bias = b_hh[i];
#pragma unroll
    for (int b = 0; b < B_; ++b) acc[b] = bias;
#pragma unroll 4
    for (int j = 0; j < D_; ++j) {
      float w = W_hhT[(size_t)j * 768 + i];
#pragma unroll
      for (int b = 0; b < B_; ++b) acc[b] += xs[b][j] * w;
    }
#pragma unroll
    for (int b = 0; b < B_; ++b) gh[(size_t)b * 768 + i] = acc[b];
  } else {
#pragma unroll
    for (int b = 0; b < B_; ++b) xs[b][tid] = hidden[b * D_ + tid];
    __syncthreads();
#pragma unroll
    for (int b = 0; b < B_; ++b) acc[b] = 0.f;
#pragma unroll 4
    for (int j = 0; j < D_; ++j) {
      float w = TQK[(size_t)j * D_ + tid];
#pragma unroll
      for (int b = 0; b < B_; ++b) acc[b] += xs[b][j] * w;
    }
#pragma unroll
    for (int b = 0; b < B_; ++b) tvec[b * D_ + tid] = acc[b];
  }
}

// ---------------- K_seq2: attention + GRU + hops (grid=16) ------------------
__global__ __launch_bounds__(256) void k_seq2(
    const float* __restrict__ part, const float* __restrict__ tvec,
    const float* __restrict__ gi, const float* __restrict__ gh,
    const float* __restrict__ hidden, const float* __restrict__ Wv,
    const float* __restrict__ S, float* __restrict__ h_new_out,
    float* __restrict__ cat, float* __restrict__ p_ptr) {
  int b = blockIdx.x, tid = threadIdx.x;
  int lane = tid & 63, wave = tid >> 6;
  __shared__ float ts[D_], wsh[NT], rs[D_], feat_s[D_], us[D_], lo[M_], pr[M_];
  ts[tid] = tvec[b * D_ + tid];
  __syncthreads();
  // scores: wave-per-root-row, 16 rows per wave, coalesced float4
  {
    float4 tsv = ((const float4*)ts)[lane];
    for (int s = 0; s < 16; ++s) {
      int n = wave * 16 + s;
      const float4* p0 = (const float4*)(part + ((size_t)(b * NT + n) * 2) * D_);
      const float4* p1 = (const float4*)(part + ((size_t)(b * NT + n) * 2 + 1) * D_);
      float4 a0 = p0[lane], a1 = p1[lane];
      float r0 = a0.x + a1.x, r1 = a0.y + a1.y, r2 = a0.z + a1.z,
            r3 = a0.w + a1.w;
      float sc = r0 * tsv.x + r1 * tsv.y + r2 * tsv.z + r3 * tsv.w;
      float sm = r0 + r1 + r2 + r3;
      for (int o = 32; o > 0; o >>= 1) {
        sc += __shfl_xor(sc, o);
        sm += __shfl_xor(sm, o);
      }
      if (lane == 0) wsh[n] = (sm == 0.0f) ? sc - 1000000000.0f : sc;
    }
  }
  __syncthreads();
  if (tid < NT) {  // softmax over 64 roots (wave 0)
    float s = wsh[tid];
    float m = s;
    for (int o = 32; o > 0; o >>= 1) m = fmaxf(m, __shfl_xor(m, o));
    float e = expf(s - m);
    float sum = e;
    for (int o = 32; o > 0; o >>= 1) sum += __shfl_xor(sum, o);
    wsh[tid] = e / sum;
  }
  __syncthreads();
  // rbar: thread-per-d, coalesced sweep over n
  {
    float rb = 0.f;
#pragma unroll 8
    for (int n = 0; n < NT; ++n) {
      const float* p = part + ((size_t)(b * NT + n) * 2) * D_;
      rb += wsh[n] * (p[tid] + p[D_ + tid]);
    }
    rs[tid] = rb;
  }
  __syncthreads();
  // feat = rbar @ Wv^T : wave-per-row
  {
    float4 rsv = ((const float4*)rs)[lane];
    for (int rr = 0; rr < 64; ++rr) {
      int r = wave * 64 + rr;
      float4 w = ((const float4*)(Wv + (size_t)r * D_))[lane];
      float d = w.x * rsv.x + w.y * rsv.y + w.z * rsv.z + w.w * rsv.w;
      for (int o = 32; o > 0; o >>= 1) d += __shfl_xor(d, o);
      if (lane == 0) feat_s[r] = d;
    }
  }
  __syncthreads();
  // GRU (gates precomputed)
  {
    float i_r = gi[(size_t)b * 768 + tid];
    float i_z = gi[(size_t)b * 768 + 256 + tid];
    float i_n = gi[(size_t)b * 768 + 512 + tid];
    float h_r = gh[(size_t)b * 768 + tid];
    float h_z = gh[(size_t)b * 768 + 256 + tid];
    float h_n = gh[(size_t)b * 768 + 512 + tid];
    float h = hidden[b * D_ + tid];
    float r = 1.f / (1.f + expf(-(i_r + h_r)));
    float z = 1.f / (1.f + expf(-(i_z + h_z)));
    float nn = tanhf(i_n + r * h_n);
    float hn = (1.f - z) * nn + z * h;
    h_new_out[b * D_ + tid] = hn;
    float u0 = hn + feat_s[tid];
    us[tid] = u0;
    cat[b * 512 + tid] = u0;
  }
  __syncthreads();
  // hops
  for (int h = 0; h < 3; ++h) {
    {  // logits: wave-per-row (32 rows per wave), coalesced float4
      float4 usv = ((const float4*)us)[lane];
      for (int rr = 0; rr < 32; ++rr) {
        int m = wave * 32 + rr;
        float4 sv =
            ((const float4*)(S + (((size_t)h * B_ + b) * M_ + m) * D_))[lane];
        float d = sv.x * usv.x + sv.y * usv.y + sv.z * usv.z + sv.w * usv.w;
        for (int o = 32; o > 0; o >>= 1) d += __shfl_xor(d, o);
        if (lane == 0) lo[m] = d;
      }
    }
    __syncthreads();
    if (h == 2) {
      if (tid < M_) p_ptr[b * M_ + tid] = lo[tid];
      break;
    }
    if (tid < 64) {  // softmax over 128 (wave 0, 2 per lane)
      float a = fmaxf(lo[tid], lo[tid + 64]);
      for (int o = 32; o > 0; o >>= 1) a = fmaxf(a, __shfl_xor(a, o));
      float e0 = expf(lo[tid] - a), e1 = expf(lo[tid + 64] - a);
      float s = e0 + e1;
      for (int o = 32; o > 0; o >>= 1) s += __shfl_xor(s, o);
      pr[tid] = e0 / s;
      pr[tid + 64] = e1 / s;
    }
    __syncthreads();
    {  // o: thread-per-d coalesced sweep over m
      const float* Sn = S + (((size_t)(h + 1) * B_ + b) * M_) * D_;
      float o = 0.f;
#pragma unroll 8
      for (int m = 0; m < M_; ++m) o += pr[m] * Sn[(size_t)m * D_ + tid];
      if (h == 0) cat[b * 512 + D_ + tid] = o;
      us[tid] += o;
    }
    __syncthreads();
  }
}

// ---------------- K_pvocab: p_vocab = cat @ W1_w^T + b ----------------------
__global__ __launch_bounds__(128) void k_pvocab(
    const float* __restrict__ cat, const float* __restrict__ W1_w,
    const float* __restrict__ W1_b, float* __restrict__ out) {
  int v = blockIdx.x * 128 + threadIdx.x;
  __shared__ float cs[B_ * 512];
  for (int i = threadIdx.x; i < B_ * 512; i += 128) cs[i] = cat[i];
  __syncthreads();
  const float4* wrow = (const float4*)(W1_w + (size_t)v * 512);
  float acc[B_];
#pragma unroll
  for (int b = 0; b < B_; ++b) acc[b] = 0.f;
  for (int k4 = 0; k4 < 128; ++k4) {
    float4 w = wrow[k4];
#pragma unroll
    for (int b = 0; b < B_; ++b) {
      const float* c = &cs[b * 512 + k4 * 4];
      acc[b] += w.x * c[0] + w.y * c[1] + w.z * c[2] + w.w * c[3];
    }
  }
  float bb = W1_b[v];
#pragma unroll
  for (int b = 0; b < B_; ++b) out[(size_t)b * VOCAB_ + v] = acc[b] + bb;
}

extern "C" void kernel_launch(void* const* d_in, const int* in_sizes, int n_in,
                              void* d_out, int out_size, void* d_ws,
                              size_t ws_size, hipStream_t stream) {
  const int* decoder_input = (const int*)d_in[0];
  const int* story = (const int*)d_in[1];
  const float* hidden = (const float*)d_in[2];
  const int* kb_values = (const int*)d_in[3];
  const int* kb_types = (const int*)d_in[4];
  const float* C = (const float*)d_in[7];
  const float* T_emb = (const float*)d_in[8];
  const float* Wq = (const float*)d_in[9];
  const float* Wk = (const float*)d_in[10];
  const float* Wv = (const float*)d_in[11];
  const float* W1_w = (const float*)d_in[12];
  const float* W1_b = (const float*)d_in[13];
  const float* W_ih = (const float*)d_in[14];
  const float* W_hh = (const float*)d_in[15];
  const float* b_ih = (const float*)d_in[16];
  const float* b_hh = (const float*)d_in[17];

  float* out = (float*)d_out;
  float* p_ptr = out;                          // (16,128)
  float* p_vocab = out + B_ * M_;              // (16,32000)
  float* h_new = out + B_ * M_ + B_ * VOCAB_;  // (16,256)

  // workspace layout (floats)
  float* ws = (float*)d_ws;
  float* S = ws;                         // 1,572,864
  float* part = S + 3 * B_ * M_ * D_;    //   524,288
  float* cat = part + B_ * NT * 2 * D_;  //     8,192
  float* W_ihT = cat + B_ * 512;         //   196,608
  float* W_hhT = W_ihT + 768 * D_;       //   196,608
  float* TQK = W_hhT + 768 * D_;         //    65,536
  float* gi = TQK + D_ * D_;             //    12,288
  float* gh = gi + B_ * 768;             //    12,288
  float* tvec = gh + B_ * 768;           //     4,096
  ushort_t* C0h = (ushort_t*)(tvec + B_ * D_);  // 8,192,000 ushorts

  hipLaunchKernelGGL(k_prep, dim3(NB_S + NB_CONV + 2 * NB_TR + 256), dim3(256),
                     0, stream, story, C, W_ih, W_hh, Wq, Wk, S, C0h, W_ihT,
                     W_hhT, TQK);
  hipLaunchKernelGGL(k_roots, dim3(2 * B_ * NT), dim3(256), 0, stream,
                     kb_values, kb_types, C0h, T_emb, part);
  hipLaunchKernelGGL(k_gates, dim3(7), dim3(256), 0, stream, decoder_input, C,
                     hidden, W_ihT, W_hhT, TQK, b_ih, b_hh, gi, gh, tvec);
  hipLaunchKernelGGL(k_seq2, dim3(B_), dim3(256), 0, stream, part, tvec, gi,
                     gh, hidden, Wv, S, h_new, cat, p_ptr);
  hipLaunchKernelGGL(k_pvocab, dim3(VOCAB_ / 128), dim3(128), 0, stream, cat,
                     W1_w, W1_b, p_vocab);
}

// Round 4
// 422.876 us; speedup vs baseline: 1.3264x; 1.1355x over previous
//
#include <hip/hip_runtime.h>
#include <hip/hip_bf16.h>
#include <math.h>

#define B_ 16
#define NT 64
#define LN 256
#define LV 4
#define D_ 256
#define VOCAB_ 32000
#define M_ 128
#define LS 4

typedef unsigned short ushort_t;
typedef unsigned int uint_t;

__device__ __forceinline__ ushort_t f2bf(float f) {
  uint_t u = __float_as_uint(f);
  uint_t r = u + 0x7FFFu + ((u >> 16) & 1u);
  return (ushort_t)(r >> 16);
}
__device__ __forceinline__ float bf2f(ushort_t h) {
  return __uint_as_float(((uint_t)h) << 16);
}

// ---------------- K_prep: S gather | C0->bf16 | W_ih^T | W_hh^T | TQK | WvT -
#define NB_S (3 * B_ * M_)  // 6144
#define NB_CONV 2048
#define NB_TR 192   // 768x256 -> 24x8 tiles of 32x32 (per weight)
#define NB_TQK 256
#define NB_WVT 64   // 256x256 -> 8x8 tiles
__global__ __launch_bounds__(256) void k_prep(
    const int* __restrict__ story, const float* __restrict__ C,
    const float* __restrict__ W_ih, const float* __restrict__ W_hh,
    const float* __restrict__ Wq, const float* __restrict__ Wk,
    const float* __restrict__ Wv, float* __restrict__ S,
    ushort_t* __restrict__ C0h, float* __restrict__ W_ihT,
    float* __restrict__ W_hhT, float* __restrict__ TQK,
    float* __restrict__ WvT) {
  __shared__ float smem[32 * 33];
  int blk = blockIdx.x, tid = threadIdx.x;
  if (blk < NB_S) {
    int h = blk / (B_ * M_);
    int bm = blk % (B_ * M_);
    const int* st = story + (size_t)bm * LS;
    const float* Ch = C + (size_t)h * VOCAB_ * D_;
    float s = Ch[(size_t)st[0] * D_ + tid] + Ch[(size_t)st[1] * D_ + tid] +
              Ch[(size_t)st[2] * D_ + tid] + Ch[(size_t)st[3] * D_ + tid];
    S[(size_t)blk * D_ + tid] = s;
  } else if (blk < NB_S + NB_CONV) {
    int n4 = VOCAB_ * D_ / 4;
    for (int i = (blk - NB_S) * 256 + tid; i < n4; i += NB_CONV * 256) {
      float4 f = ((const float4*)C)[i];
      uint2 packed;
      packed.x = (uint_t)f2bf(f.x) | ((uint_t)f2bf(f.y) << 16);
      packed.y = (uint_t)f2bf(f.z) | ((uint_t)f2bf(f.w) << 16);
      ((uint2*)C0h)[i] = packed;
    }
  } else if (blk < NB_S + NB_CONV + 2 * NB_TR) {
    int t = blk - (NB_S + NB_CONV);
    const float* W = W_ih;
    float* WT = W_ihT;
    if (t >= NB_TR) { t -= NB_TR; W = W_hh; WT = W_hhT; }
    const int R = 768;
    int tr = t % (R / 32), tc = t / (R / 32);
    int tx = tid & 31, ty = tid >> 5;
#pragma unroll
    for (int k = 0; k < 4; ++k)
      smem[(ty + 8 * k) * 33 + tx] =
          W[(size_t)(tr * 32 + ty + 8 * k) * D_ + tc * 32 + tx];
    __syncthreads();
#pragma unroll
    for (int k = 0; k < 4; ++k)
      WT[(size_t)(tc * 32 + ty + 8 * k) * R + tr * 32 + tx] =
          smem[tx * 33 + ty + 8 * k];
  } else if (blk < NB_S + NB_CONV + 2 * NB_TR + NB_TQK) {
    // TQK[j,i] = sum_k Wq[k,j] * Wk[k,i]
    int j = blk - (NB_S + NB_CONV + 2 * NB_TR);
    smem[tid] = Wq[(size_t)tid * D_ + j];
    __syncthreads();
    float acc = 0.f;
#pragma unroll 8
    for (int k = 0; k < D_; ++k) acc += smem[k] * Wk[(size_t)k * D_ + tid];
    TQK[(size_t)j * D_ + tid] = acc;
  } else {
    // WvT[j,r] = Wv[r,j]
    int t = blk - (NB_S + NB_CONV + 2 * NB_TR + NB_TQK);
    int tr = t & 7, tc = t >> 3;
    int tx = tid & 31, ty = tid >> 5;
#pragma unroll
    for (int k = 0; k < 4; ++k)
      smem[(ty + 8 * k) * 33 + tx] =
          Wv[(size_t)(tr * 32 + ty + 8 * k) * D_ + tc * 32 + tx];
    __syncthreads();
#pragma unroll
    for (int k = 0; k < 4; ++k)
      WvT[(size_t)(tc * 32 + ty + 8 * k) * D_ + tr * 32 + tx] =
          smem[tx * 33 + ty + 8 * k];
  }
}

// ---------------- K_rootsg: roots partials (2048 blocks) + gates + tvec -----
__global__ __launch_bounds__(256) void k_rootsg(
    const int* __restrict__ kb_values, const int* __restrict__ kb_types,
    const ushort_t* __restrict__ C0h, const float* __restrict__ T_emb,
    const int* __restrict__ dec, const float* __restrict__ C0,
    const float* __restrict__ hidden, const float* __restrict__ W_ihT,
    const float* __restrict__ W_hhT, const float* __restrict__ TQK,
    const float* __restrict__ b_ih, const float* __restrict__ b_hh,
    float* __restrict__ part, float* __restrict__ gi, float* __restrict__ gh,
    float* __restrict__ tvec) {
  int blk = blockIdx.x, tid = threadIdx.x;
  if (blk < 2048) {
    int bn = blk >> 1;
    int half = blk & 1;
    __shared__ int sv[128 * LV];
    __shared__ int st[128];
    const int* vptr = kb_values + (size_t)bn * LN * LV + half * 128 * LV;
    for (int i = tid; i < 128 * LV; i += 256) sv[i] = vptr[i];
    if (tid < 128) st[tid] = kb_types[(size_t)bn * LN + half * 128 + tid];
    __syncthreads();
    float acc = 0.f;
#pragma unroll 4
    for (int l = 0; l < 128; ++l) {
      const int* v = &sv[l * LV];
      float s = bf2f(C0h[(size_t)v[0] * D_ + tid]) +
                bf2f(C0h[(size_t)v[1] * D_ + tid]) +
                bf2f(C0h[(size_t)v[2] * D_ + tid]) +
                bf2f(C0h[(size_t)v[3] * D_ + tid]);
      acc += T_emb[st[l] * D_ + tid] * s;
    }
    part[((size_t)bn * 2 + half) * D_ + tid] = acc;
  } else {
    int g = blk - 2048;  // 0..2: gi, 3..5: gh, 6: tvec
    __shared__ float xs[B_][D_];
    float acc[B_];
    if (g < 3) {
#pragma unroll
      for (int b = 0; b < B_; ++b) xs[b][tid] = C0[(size_t)dec[b] * D_ + tid];
      __syncthreads();
      int i = g * 256 + tid;
      float bias = b_ih[i];
#pragma unroll
      for (int b = 0; b < B_; ++b) acc[b] = bias;
#pragma unroll 4
      for (int j = 0; j < D_; ++j) {
        float w = W_ihT[(size_t)j * 768 + i];
#pragma unroll
        for (int b = 0; b < B_; ++b) acc[b] += xs[b][j] * w;
      }
#pragma unroll
      for (int b = 0; b < B_; ++b) gi[(size_t)b * 768 + i] = acc[b];
    } else if (g < 6) {
#pragma unroll
      for (int b = 0; b < B_; ++b) xs[b][tid] = hidden[b * D_ + tid];
      __syncthreads();
      int i = (g - 3) * 256 + tid;
      float bias = b_hh[i];
#pragma unroll
      for (int b = 0; b < B_; ++b) acc[b] = bias;
#pragma unroll 4
      for (int j = 0; j < D_; ++j) {
        float w = W_hhT[(size_t)j * 768 + i];
#pragma unroll
        for (int b = 0; b < B_; ++b) acc[b] += xs[b][j] * w;
      }
#pragma unroll
      for (int b = 0; b < B_; ++b) gh[(size_t)b * 768 + i] = acc[b];
    } else {
#pragma unroll
      for (int b = 0; b < B_; ++b) xs[b][tid] = hidden[b * D_ + tid];
      __syncthreads();
#pragma unroll
      for (int b = 0; b < B_; ++b) acc[b] = 0.f;
#pragma unroll 4
      for (int j = 0; j < D_; ++j) {
        float w = TQK[(size_t)j * D_ + tid];
#pragma unroll
        for (int b = 0; b < B_; ++b) acc[b] += xs[b][j] * w;
      }
#pragma unroll
      for (int b = 0; b < B_; ++b) tvec[b * D_ + tid] = acc[b];
    }
  }
}

// ---------------- K_mid: scores (1024 blocks) + S transpose (1536 blocks) ---
__global__ __launch_bounds__(256) void k_mid(
    const float* __restrict__ part, const float* __restrict__ tvec,
    const float* __restrict__ S, float* __restrict__ scores,
    float* __restrict__ ST) {
  int blk = blockIdx.x, tid = threadIdx.x;
  if (blk < 1024) {
    int b = blk >> 6;
    const float* p = part + (size_t)blk * 2 * D_;
    float rv = p[tid] + p[D_ + tid];
    float sc = rv * tvec[b * D_ + tid];
    float sm = rv;
    __shared__ float red[8];
    int lane = tid & 63, wave = tid >> 6;
    for (int o = 32; o > 0; o >>= 1) {
      sc += __shfl_xor(sc, o);
      sm += __shfl_xor(sm, o);
    }
    if (lane == 0) { red[wave] = sc; red[4 + wave] = sm; }
    __syncthreads();
    if (tid == 0) {
      float SC = red[0] + red[1] + red[2] + red[3];
      float SM = red[4] + red[5] + red[6] + red[7];
      scores[blk] = (SM == 0.0f) ? SC - 1000000000.0f : SC;
    }
  } else {
    // ST[hb][d][m] = S[hb][m][d]; 32 tiles (4 m-tiles x 8 d-tiles) per hb
    int t = blk - 1024;
    int hb = t >> 5;
    int tile = t & 31;
    int tm = tile & 3, td = tile >> 2;
    int tx = tid & 31, ty = tid >> 5;
    __shared__ float sm2[32 * 33];
    const float* Sp = S + (size_t)hb * M_ * D_;
    float* STp = ST + (size_t)hb * D_ * M_;
#pragma unroll
    for (int k = 0; k < 4; ++k)
      sm2[(ty + 8 * k) * 33 + tx] =
          Sp[(size_t)(tm * 32 + ty + 8 * k) * D_ + td * 32 + tx];
    __syncthreads();
#pragma unroll
    for (int k = 0; k < 4; ++k)
      STp[(size_t)(td * 32 + ty + 8 * k) * M_ + tm * 32 + tx] =
          sm2[tx * 33 + ty + 8 * k];
  }
}

// ---------------- K_chain: softmax/rbar/feat/GRU/hops (grid=16) -------------
__global__ __launch_bounds__(256) void k_chain(
    const float* __restrict__ scores, const float* __restrict__ part,
    const float* __restrict__ WvT, const float* __restrict__ gi,
    const float* __restrict__ gh, const float* __restrict__ hidden,
    const float* __restrict__ S, const float* __restrict__ ST,
    float* __restrict__ h_new_out, float* __restrict__ cat,
    float* __restrict__ p_ptr) {
  int b = blockIdx.x, tid = threadIdx.x;
  __shared__ float wsh[NT], rs[D_], us[D_], lo[M_], loB[M_], pr[M_];
  if (tid < NT) {  // softmax over 64 roots (wave 0)
    float s = scores[b * NT + tid];
    float m = s;
    for (int o = 32; o > 0; o >>= 1) m = fmaxf(m, __shfl_xor(m, o));
    float e = expf(s - m);
    float sum = e;
    for (int o = 32; o > 0; o >>= 1) sum += __shfl_xor(sum, o);
    wsh[tid] = e / sum;
  }
  __syncthreads();
  // rbar: thread-per-d coalesced sweep over n
  float rb = 0.f;
#pragma unroll 8
  for (int n = 0; n < NT; ++n) {
    const float* p = part + ((size_t)(b * NT + n) * 2) * D_;
    rb += wsh[n] * (p[tid] + p[D_ + tid]);
  }
  rs[tid] = rb;
  __syncthreads();
  // feat[r] = sum_j rs[j] * WvT[j][r]  (coalesced over r=tid)
  float feat = 0.f;
#pragma unroll 8
  for (int j = 0; j < D_; ++j) feat += rs[j] * WvT[(size_t)j * D_ + tid];
  // GRU (gates precomputed)
  {
    float i_r = gi[(size_t)b * 768 + tid];
    float i_z = gi[(size_t)b * 768 + 256 + tid];
    float i_n = gi[(size_t)b * 768 + 512 + tid];
    float h_r = gh[(size_t)b * 768 + tid];
    float h_z = gh[(size_t)b * 768 + 256 + tid];
    float h_n = gh[(size_t)b * 768 + 512 + tid];
    float h = hidden[b * D_ + tid];
    float r = 1.f / (1.f + expf(-(i_r + h_r)));
    float z = 1.f / (1.f + expf(-(i_z + h_z)));
    float nn = tanhf(i_n + r * h_n);
    float hn = (1.f - z) * nn + z * h;
    h_new_out[b * D_ + tid] = hn;
    float u0 = hn + feat;
    us[tid] = u0;
    cat[b * 512 + tid] = u0;
  }
  __syncthreads();
  // hops
  for (int h = 0; h < 3; ++h) {
    {  // logits: thread half 0 sums d=0..127, half 1 sums d=128..255
      int m = tid & 127;
      int half = tid >> 7;
      const float* STp = ST + (((size_t)h * B_ + b) * D_ + half * 128) * M_;
      float l = 0.f;
#pragma unroll 8
      for (int d = 0; d < 128; ++d)
        l += us[half * 128 + d] * STp[(size_t)d * M_ + m];
      if (half == 0) lo[m] = l; else loB[m] = l;
    }
    __syncthreads();
    if (h == 2) {
      if (tid < M_) p_ptr[b * M_ + tid] = lo[tid] + loB[tid];
      break;
    }
    if (tid < 64) {  // softmax over 128 (wave 0, 2 per lane)
      float l0 = lo[tid] + loB[tid], l1 = lo[tid + 64] + loB[tid + 64];
      float a = fmaxf(l0, l1);
      for (int o = 32; o > 0; o >>= 1) a = fmaxf(a, __shfl_xor(a, o));
      float e0 = expf(l0 - a), e1 = expf(l1 - a);
      float s = e0 + e1;
      for (int o = 32; o > 0; o >>= 1) s += __shfl_xor(s, o);
      pr[tid] = e0 / s;
      pr[tid + 64] = e1 / s;
    }
    __syncthreads();
    {  // o: thread-per-d coalesced sweep over m
      const float* Sn = S + (((size_t)(h + 1) * B_ + b) * M_) * D_;
      float o = 0.f;
#pragma unroll 8
      for (int m = 0; m < M_; ++m) o += pr[m] * Sn[(size_t)m * D_ + tid];
      if (h == 0) cat[b * 512 + D_ + tid] = o;
      us[tid] += o;
    }
    __syncthreads();
  }
}

// ---------------- K_pvocab: p_vocab = cat @ W1_w^T + b ----------------------
__global__ __launch_bounds__(128) void k_pvocab(
    const float* __restrict__ cat, const float* __restrict__ W1_w,
    const float* __restrict__ W1_b, float* __restrict__ out) {
  int v = blockIdx.x * 128 + threadIdx.x;
  __shared__ float cs[B_ * 512];
  for (int i = threadIdx.x; i < B_ * 512; i += 128) cs[i] = cat[i];
  __syncthreads();
  const float4* wrow = (const float4*)(W1_w + (size_t)v * 512);
  float acc[B_];
#pragma unroll
  for (int b = 0; b < B_; ++b) acc[b] = 0.f;
  for (int k4 = 0; k4 < 128; ++k4) {
    float4 w = wrow[k4];
#pragma unroll
    for (int b = 0; b < B_; ++b) {
      const float* c = &cs[b * 512 + k4 * 4];
      acc[b] += w.x * c[0] + w.y * c[1] + w.z * c[2] + w.w * c[3];
    }
  }
  float bb = W1_b[v];
#pragma unroll
  for (int b = 0; b < B_; ++b) out[(size_t)b * VOCAB_ + v] = acc[b] + bb;
}

extern "C" void kernel_launch(void* const* d_in, const int* in_sizes, int n_in,
                              void* d_out, int out_size, void* d_ws,
                              size_t ws_size, hipStream_t stream) {
  const int* decoder_input = (const int*)d_in[0];
  const int* story = (const int*)d_in[1];
  const float* hidden = (const float*)d_in[2];
  const int* kb_values = (const int*)d_in[3];
  const int* kb_types = (const int*)d_in[4];
  const float* C = (const float*)d_in[7];
  const float* T_emb = (const float*)d_in[8];
  const float* Wq = (const float*)d_in[9];
  const float* Wk = (const float*)d_in[10];
  const float* Wv = (const float*)d_in[11];
  const float* W1_w = (const float*)d_in[12];
  const float* W1_b = (const float*)d_in[13];
  const float* W_ih = (const float*)d_in[14];
  const float* W_hh = (const float*)d_in[15];
  const float* b_ih = (const float*)d_in[16];
  const float* b_hh = (const float*)d_in[17];

  float* out = (float*)d_out;
  float* p_ptr = out;                          // (16,128)
  float* p_vocab = out + B_ * M_;              // (16,32000)
  float* h_new = out + B_ * M_ + B_ * VOCAB_;  // (16,256)

  // workspace layout (floats). ST aliases W_ihT/W_hhT/TQK (dead by then).
  float* ws = (float*)d_ws;
  float* S = ws;                          // 1,572,864
  float* part = S + 3 * B_ * M_ * D_;     //   524,288
  float* cat = part + B_ * NT * 2 * D_;   //     8,192
  float* scores = cat + B_ * 512;         //     1,024
  float* gi = scores + B_ * NT;           //    12,288
  float* gh = gi + B_ * 768;              //    12,288
  float* tvec = gh + B_ * 768;            //     4,096
  ushort_t* C0h = (ushort_t*)(tvec + B_ * D_);   // 8,192,000 ushorts
  float* wtmp = (float*)(C0h + (size_t)VOCAB_ * D_);
  float* W_ihT = wtmp;                    //   196,608
  float* W_hhT = W_ihT + 768 * D_;        //   196,608
  float* TQK = W_hhT + 768 * D_;          //    65,536
  float* ST = wtmp;                       // alias: 1,572,864
  float* WvT = wtmp + 3 * B_ * M_ * D_;   //    65,536 (after ST region)

  hipLaunchKernelGGL(k_prep,
                     dim3(NB_S + NB_CONV + 2 * NB_TR + NB_TQK + NB_WVT),
                     dim3(256), 0, stream, story, C, W_ih, W_hh, Wq, Wk, Wv, S,
                     C0h, W_ihT, W_hhT, TQK, WvT);
  hipLaunchKernelGGL(k_rootsg, dim3(2048 + 7), dim3(256), 0, stream, kb_values,
                     kb_types, C0h, T_emb, decoder_input, C, hidden, W_ihT,
                     W_hhT, TQK, b_ih, b_hh, part, gi, gh, tvec);
  hipLaunchKernelGGL(k_mid, dim3(1024 + 1536), dim3(256), 0, stream, part,
                     tvec, S, scores, ST);
  hipLaunchKernelGGL(k_chain, dim3(B_), dim3(256), 0, stream, scores, part,
                     WvT, gi, gh, hidden, S, ST, h_new, cat, p_ptr);
  hipLaunchKernelGGL(k_pvocab, dim3(VOCAB_ / 128), dim3(128), 0, stream, cat,
                     W1_w, W1_b, p_vocab);
}

// Round 5
// 416.359 us; speedup vs baseline: 1.3471x; 1.0157x over previous
//
#include <hip/hip_runtime.h>
#include <hip/hip_bf16.h>
#include <math.h>

#define B_ 16
#define NT 64
#define LN 256
#define LV 4
#define D_ 256
#define VOCAB_ 32000
#define M_ 128
#define LS 4

typedef unsigned short ushort_t;
typedef unsigned int uint_t;

__device__ __forceinline__ ushort_t f2bf(float f) {
  uint_t u = __float_as_uint(f);
  uint_t r = u + 0x7FFFu + ((u >> 16) & 1u);
  return (ushort_t)(r >> 16);
}
__device__ __forceinline__ float bflo(uint_t u) {
  return __uint_as_float(u << 16);
}
__device__ __forceinline__ float bfhi(uint_t u) {
  return __uint_as_float(u & 0xFFFF0000u);
}

// ---------------- K_prep: S gather | C0->bf16 | W_ih^T | W_hh^T | TQK | WvT -
#define NB_S (3 * B_ * M_)  // 6144
#define NB_CONV 2048
#define NB_TR 192   // 768x256 -> 24x8 tiles of 32x32 (per weight)
#define NB_TQK 256
#define NB_WVT 64   // 256x256 -> 8x8 tiles
__global__ __launch_bounds__(256) void k_prep(
    const int* __restrict__ story, const float* __restrict__ C,
    const float* __restrict__ W_ih, const float* __restrict__ W_hh,
    const float* __restrict__ Wq, const float* __restrict__ Wk,
    const float* __restrict__ Wv, float* __restrict__ S,
    ushort_t* __restrict__ C0h, float* __restrict__ W_ihT,
    float* __restrict__ W_hhT, float* __restrict__ TQK,
    float* __restrict__ WvT) {
  __shared__ float smem[32 * 33];
  int blk = blockIdx.x, tid = threadIdx.x;
  if (blk < NB_S) {
    int h = blk / (B_ * M_);
    int bm = blk % (B_ * M_);
    const int* st = story + (size_t)bm * LS;
    const float* Ch = C + (size_t)h * VOCAB_ * D_;
    float s = Ch[(size_t)st[0] * D_ + tid] + Ch[(size_t)st[1] * D_ + tid] +
              Ch[(size_t)st[2] * D_ + tid] + Ch[(size_t)st[3] * D_ + tid];
    S[(size_t)blk * D_ + tid] = s;
  } else if (blk < NB_S + NB_CONV) {
    int n4 = VOCAB_ * D_ / 4;
    for (int i = (blk - NB_S) * 256 + tid; i < n4; i += NB_CONV * 256) {
      float4 f = ((const float4*)C)[i];
      uint2 packed;
      packed.x = (uint_t)f2bf(f.x) | ((uint_t)f2bf(f.y) << 16);
      packed.y = (uint_t)f2bf(f.z) | ((uint_t)f2bf(f.w) << 16);
      ((uint2*)C0h)[i] = packed;
    }
  } else if (blk < NB_S + NB_CONV + 2 * NB_TR) {
    int t = blk - (NB_S + NB_CONV);
    const float* W = W_ih;
    float* WT = W_ihT;
    if (t >= NB_TR) { t -= NB_TR; W = W_hh; WT = W_hhT; }
    const int R = 768;
    int tr = t % (R / 32), tc = t / (R / 32);
    int tx = tid & 31, ty = tid >> 5;
#pragma unroll
    for (int k = 0; k < 4; ++k)
      smem[(ty + 8 * k) * 33 + tx] =
          W[(size_t)(tr * 32 + ty + 8 * k) * D_ + tc * 32 + tx];
    __syncthreads();
#pragma unroll
    for (int k = 0; k < 4; ++k)
      WT[(size_t)(tc * 32 + ty + 8 * k) * R + tr * 32 + tx] =
          smem[tx * 33 + ty + 8 * k];
  } else if (blk < NB_S + NB_CONV + 2 * NB_TR + NB_TQK) {
    // TQK[j,i] = sum_k Wq[k,j] * Wk[k,i]
    int j = blk - (NB_S + NB_CONV + 2 * NB_TR);
    smem[tid] = Wq[(size_t)tid * D_ + j];
    __syncthreads();
    float acc = 0.f;
#pragma unroll 8
    for (int k = 0; k < D_; ++k) acc += smem[k] * Wk[(size_t)k * D_ + tid];
    TQK[(size_t)j * D_ + tid] = acc;
  } else {
    // WvT[j,r] = Wv[r,j]
    int t = blk - (NB_S + NB_CONV + 2 * NB_TR + NB_TQK);
    int tr = t & 7, tc = t >> 3;
    int tx = tid & 31, ty = tid >> 5;
#pragma unroll
    for (int k = 0; k < 4; ++k)
      smem[(ty + 8 * k) * 33 + tx] =
          Wv[(size_t)(tr * 32 + ty + 8 * k) * D_ + tc * 32 + tx];
    __syncthreads();
#pragma unroll
    for (int k = 0; k < 4; ++k)
      WvT[(size_t)(tc * 32 + ty + 8 * k) * D_ + tr * 32 + tx] =
          smem[tx * 33 + ty + 8 * k];
  }
}

// ---------------- K_rootsg: roots partials (wave-per-row) + gates + tvec ----
__global__ __launch_bounds__(256) void k_rootsg(
    const int* __restrict__ kb_values, const int* __restrict__ kb_types,
    const ushort_t* __restrict__ C0h, const float* __restrict__ T_emb,
    const int* __restrict__ dec, const float* __restrict__ C0,
    const float* __restrict__ hidden, const float* __restrict__ W_ihT,
    const float* __restrict__ W_hhT, const float* __restrict__ TQK,
    const float* __restrict__ b_ih, const float* __restrict__ b_hh,
    float* __restrict__ part, float* __restrict__ gi, float* __restrict__ gh,
    float* __restrict__ tvec) {
  int blk = blockIdx.x, tid = threadIdx.x;
  if (blk < 2048) {
    int bn = blk >> 1;
    int half = blk & 1;
    int lane = tid & 63, team = tid >> 6;
    __shared__ int sv[128 * LV];
    __shared__ int st[128];
    __shared__ float psum[4][D_];
    const int* vptr = kb_values + (size_t)bn * LN * LV + half * 128 * LV;
    for (int i = tid; i < 128 * LV; i += 256) sv[i] = vptr[i];
    if (tid < 128) st[tid] = kb_types[(size_t)bn * LN + half * 128 + tid];
    __syncthreads();
    // each lane owns columns 4*lane..4*lane+3; team handles 32 leaves
    float a0 = 0.f, a1 = 0.f, a2 = 0.f, a3 = 0.f;
#pragma unroll 2
    for (int li = 0; li < 32; ++li) {
      int l = team * 32 + li;
      const int* v = &sv[l * LV];
      uint2 u0 = ((const uint2*)(C0h + (size_t)v[0] * D_))[lane];
      uint2 u1 = ((const uint2*)(C0h + (size_t)v[1] * D_))[lane];
      uint2 u2 = ((const uint2*)(C0h + (size_t)v[2] * D_))[lane];
      uint2 u3 = ((const uint2*)(C0h + (size_t)v[3] * D_))[lane];
      float4 t4 = ((const float4*)(T_emb + (size_t)st[l] * D_))[lane];
      float s0 = bflo(u0.x) + bflo(u1.x) + bflo(u2.x) + bflo(u3.x);
      float s1 = bfhi(u0.x) + bfhi(u1.x) + bfhi(u2.x) + bfhi(u3.x);
      float s2 = bflo(u0.y) + bflo(u1.y) + bflo(u2.y) + bflo(u3.y);
      float s3 = bfhi(u0.y) + bfhi(u1.y) + bfhi(u2.y) + bfhi(u3.y);
      a0 += t4.x * s0;
      a1 += t4.y * s1;
      a2 += t4.z * s2;
      a3 += t4.w * s3;
    }
    psum[team][4 * lane + 0] = a0;
    psum[team][4 * lane + 1] = a1;
    psum[team][4 * lane + 2] = a2;
    psum[team][4 * lane + 3] = a3;
    __syncthreads();
    float r = psum[0][tid] + psum[1][tid] + psum[2][tid] + psum[3][tid];
    part[((size_t)bn * 2 + half) * D_ + tid] = r;
  } else {
    int g = blk - 2048;  // 0..2: gi, 3..5: gh, 6: tvec
    __shared__ float xs[B_][D_];
    float acc[B_];
    if (g < 3) {
#pragma unroll
      for (int b = 0; b < B_; ++b) xs[b][tid] = C0[(size_t)dec[b] * D_ + tid];
      __syncthreads();
      int i = g * 256 + tid;
      float bias = b_ih[i];
#pragma unroll
      for (int b = 0; b < B_; ++b) acc[b] = bias;
#pragma unroll 4
      for (int j = 0; j < D_; ++j) {
        float w = W_ihT[(size_t)j * 768 + i];
#pragma unroll
        for (int b = 0; b < B_; ++b) acc[b] += xs[b][j] * w;
      }
#pragma unroll
      for (int b = 0; b < B_; ++b) gi[(size_t)b * 768 + i] = acc[b];
    } else if (g < 6) {
#pragma unroll
      for (int b = 0; b < B_; ++b) xs[b][tid] = hidden[b * D_ + tid];
      __syncthreads();
      int i = (g - 3) * 256 + tid;
      float bias = b_hh[i];
#pragma unroll
      for (int b = 0; b < B_; ++b) acc[b] = bias;
#pragma unroll 4
      for (int j = 0; j < D_; ++j) {
        float w = W_hhT[(size_t)j * 768 + i];
#pragma unroll
        for (int b = 0; b < B_; ++b) acc[b] += xs[b][j] * w;
      }
#pragma unroll
      for (int b = 0; b < B_; ++b) gh[(size_t)b * 768 + i] = acc[b];
    } else {
#pragma unroll
      for (int b = 0; b < B_; ++b) xs[b][tid] = hidden[b * D_ + tid];
      __syncthreads();
#pragma unroll
      for (int b = 0; b < B_; ++b) acc[b] = 0.f;
#pragma unroll 4
      for (int j = 0; j < D_; ++j) {
        float w = TQK[(size_t)j * D_ + tid];
#pragma unroll
        for (int b = 0; b < B_; ++b) acc[b] += xs[b][j] * w;
      }
#pragma unroll
      for (int b = 0; b < B_; ++b) tvec[b * D_ + tid] = acc[b];
    }
  }
}

// ---------------- K_mid: scores (1024 blocks) + S transpose (1536 blocks) ---
__global__ __launch_bounds__(256) void k_mid(
    const float* __restrict__ part, const float* __restrict__ tvec,
    const float* __restrict__ S, float* __restrict__ scores,
    float* __restrict__ ST) {
  int blk = blockIdx.x, tid = threadIdx.x;
  if (blk < 1024) {
    int b = blk >> 6;
    const float* p = part + (size_t)blk * 2 * D_;
    float rv = p[tid] + p[D_ + tid];
    float sc = rv * tvec[b * D_ + tid];
    float sm = rv;
    __shared__ float red[8];
    int lane = tid & 63, wave = tid >> 6;
    for (int o = 32; o > 0; o >>= 1) {
      sc += __shfl_xor(sc, o);
      sm += __shfl_xor(sm, o);
    }
    if (lane == 0) { red[wave] = sc; red[4 + wave] = sm; }
    __syncthreads();
    if (tid == 0) {
      float SC = red[0] + red[1] + red[2] + red[3];
      float SM = red[4] + red[5] + red[6] + red[7];
      scores[blk] = (SM == 0.0f) ? SC - 1000000000.0f : SC;
    }
  } else {
    // ST[hb][d][m] = S[hb][m][d]
    int t = blk - 1024;
    int hb = t >> 5;
    int tile = t & 31;
    int tm = tile & 3, td = tile >> 2;
    int tx = tid & 31, ty = tid >> 5;
    __shared__ float sm2[32 * 33];
    const float* Sp = S + (size_t)hb * M_ * D_;
    float* STp = ST + (size_t)hb * D_ * M_;
#pragma unroll
    for (int k = 0; k < 4; ++k)
      sm2[(ty + 8 * k) * 33 + tx] =
          Sp[(size_t)(tm * 32 + ty + 8 * k) * D_ + td * 32 + tx];
    __syncthreads();
#pragma unroll
    for (int k = 0; k < 4; ++k)
      STp[(size_t)(td * 32 + ty + 8 * k) * M_ + tm * 32 + tx] =
          sm2[tx * 33 + ty + 8 * k];
  }
}

// ---------------- K_chain: softmax/rbar/feat/GRU/hops (grid=16) -------------
__global__ __launch_bounds__(256) void k_chain(
    const float* __restrict__ scores, const float* __restrict__ part,
    const float* __restrict__ WvT, const float* __restrict__ gi,
    const float* __restrict__ gh, const float* __restrict__ hidden,
    const float* __restrict__ S, const float* __restrict__ ST,
    float* __restrict__ h_new_out, float* __restrict__ cat,
    float* __restrict__ p_ptr) {
  int b = blockIdx.x, tid = threadIdx.x;
  __shared__ float wsh[NT], rs[D_], us[D_], lo[M_], loB[M_], pr[M_];
  if (tid < NT) {
    float s = scores[b * NT + tid];
    float m = s;
    for (int o = 32; o > 0; o >>= 1) m = fmaxf(m, __shfl_xor(m, o));
    float e = expf(s - m);
    float sum = e;
    for (int o = 32; o > 0; o >>= 1) sum += __shfl_xor(sum, o);
    wsh[tid] = e / sum;
  }
  __syncthreads();
  float rb = 0.f;
#pragma unroll 8
  for (int n = 0; n < NT; ++n) {
    const float* p = part + ((size_t)(b * NT + n) * 2) * D_;
    rb += wsh[n] * (p[tid] + p[D_ + tid]);
  }
  rs[tid] = rb;
  __syncthreads();
  float feat = 0.f;
#pragma unroll 8
  for (int j = 0; j < D_; ++j) feat += rs[j] * WvT[(size_t)j * D_ + tid];
  {
    float i_r = gi[(size_t)b * 768 + tid];
    float i_z = gi[(size_t)b * 768 + 256 + tid];
    float i_n = gi[(size_t)b * 768 + 512 + tid];
    float h_r = gh[(size_t)b * 768 + tid];
    float h_z = gh[(size_t)b * 768 + 256 + tid];
    float h_n = gh[(size_t)b * 768 + 512 + tid];
    float h = hidden[b * D_ + tid];
    float r = 1.f / (1.f + expf(-(i_r + h_r)));
    float z = 1.f / (1.f + expf(-(i_z + h_z)));
    float nn = tanhf(i_n + r * h_n);
    float hn = (1.f - z) * nn + z * h;
    h_new_out[b * D_ + tid] = hn;
    float u0 = hn + feat;
    us[tid] = u0;
    cat[b * 512 + tid] = u0;
  }
  __syncthreads();
  for (int h = 0; h < 3; ++h) {
    {
      int m = tid & 127;
      int half = tid >> 7;
      const float* STp = ST + (((size_t)h * B_ + b) * D_ + half * 128) * M_;
      float l = 0.f;
#pragma unroll 8
      for (int d = 0; d < 128; ++d)
        l += us[half * 128 + d] * STp[(size_t)d * M_ + m];
      if (half == 0) lo[m] = l; else loB[m] = l;
    }
    __syncthreads();
    if (h == 2) {
      if (tid < M_) p_ptr[b * M_ + tid] = lo[tid] + loB[tid];
      break;
    }
    if (tid < 64) {
      float l0 = lo[tid] + loB[tid], l1 = lo[tid + 64] + loB[tid + 64];
      float a = fmaxf(l0, l1);
      for (int o = 32; o > 0; o >>= 1) a = fmaxf(a, __shfl_xor(a, o));
      float e0 = expf(l0 - a), e1 = expf(l1 - a);
      float s = e0 + e1;
      for (int o = 32; o > 0; o >>= 1) s += __shfl_xor(s, o);
      pr[tid] = e0 / s;
      pr[tid + 64] = e1 / s;
    }
    __syncthreads();
    {
      const float* Sn = S + (((size_t)(h + 1) * B_ + b) * M_) * D_;
      float o = 0.f;
#pragma unroll 8
      for (int m = 0; m < M_; ++m) o += pr[m] * Sn[(size_t)m * D_ + tid];
      if (h == 0) cat[b * 512 + D_ + tid] = o;
      us[tid] += o;
    }
    __syncthreads();
  }
}

// ---------------- K_pvocab: p_vocab = cat @ W1_w^T + b ----------------------
__global__ __launch_bounds__(128) void k_pvocab(
    const float* __restrict__ cat, const float* __restrict__ W1_w,
    const float* __restrict__ W1_b, float* __restrict__ out) {
  int v = blockIdx.x * 128 + threadIdx.x;
  __shared__ float cs[B_ * 512];
  for (int i = threadIdx.x; i < B_ * 512; i += 128) cs[i] = cat[i];
  __syncthreads();
  const float4* wrow = (const float4*)(W1_w + (size_t)v * 512);
  float acc[B_];
#pragma unroll
  for (int b = 0; b < B_; ++b) acc[b] = 0.f;
  for (int k4 = 0; k4 < 128; ++k4) {
    float4 w = wrow[k4];
#pragma unroll
    for (int b = 0; b < B_; ++b) {
      const float* c = &cs[b * 512 + k4 * 4];
      acc[b] += w.x * c[0] + w.y * c[1] + w.z * c[2] + w.w * c[3];
    }
  }
  float bb = W1_b[v];
#pragma unroll
  for (int b = 0; b < B_; ++b) out[(size_t)b * VOCAB_ + v] = acc[b] + bb;
}

extern "C" void kernel_launch(void* const* d_in, const int* in_sizes, int n_in,
                              void* d_out, int out_size, void* d_ws,
                              size_t ws_size, hipStream_t stream) {
  const int* decoder_input = (const int*)d_in[0];
  const int* story = (const int*)d_in[1];
  const float* hidden = (const float*)d_in[2];
  const int* kb_values = (const int*)d_in[3];
  const int* kb_types = (const int*)d_in[4];
  const float* C = (const float*)d_in[7];
  const float* T_emb = (const float*)d_in[8];
  const float* Wq = (const float*)d_in[9];
  const float* Wk = (const float*)d_in[10];
  const float* Wv = (const float*)d_in[11];
  const float* W1_w = (const float*)d_in[12];
  const float* W1_b = (const float*)d_in[13];
  const float* W_ih = (const float*)d_in[14];
  const float* W_hh = (const float*)d_in[15];
  const float* b_ih = (const float*)d_in[16];
  const float* b_hh = (const float*)d_in[17];

  float* out = (float*)d_out;
  float* p_ptr = out;                          // (16,128)
  float* p_vocab = out + B_ * M_;              // (16,32000)
  float* h_new = out + B_ * M_ + B_ * VOCAB_;  // (16,256)

  // workspace layout (floats). ST aliases W_ihT/W_hhT/TQK (dead by then).
  float* ws = (float*)d_ws;
  float* S = ws;                          // 1,572,864
  float* part = S + 3 * B_ * M_ * D_;     //   524,288
  float* cat = part + B_ * NT * 2 * D_;   //     8,192
  float* scores = cat + B_ * 512;         //     1,024
  float* gi = scores + B_ * NT;           //    12,288
  float* gh = gi + B_ * 768;              //    12,288
  float* tvec = gh + B_ * 768;            //     4,096
  ushort_t* C0h = (ushort_t*)(tvec + B_ * D_);   // 8,192,000 ushorts
  float* wtmp = (float*)(C0h + (size_t)VOCAB_ * D_);
  float* W_ihT = wtmp;                    //   196,608
  float* W_hhT = W_ihT + 768 * D_;        //   196,608
  float* TQK = W_hhT + 768 * D_;          //    65,536
  float* ST = wtmp;                       // alias: 1,572,864
  float* WvT = wtmp + 3 * B_ * M_ * D_;   //    65,536 (after ST region)

  hipLaunchKernelGGL(k_prep,
                     dim3(NB_S + NB_CONV + 2 * NB_TR + NB_TQK + NB_WVT),
                     dim3(256), 0, stream, story, C, W_ih, W_hh, Wq, Wk, Wv, S,
                     C0h, W_ihT, W_hhT, TQK, WvT);
  hipLaunchKernelGGL(k_rootsg, dim3(2048 + 7), dim3(256), 0, stream, kb_values,
                     kb_types, C0h, T_emb, decoder_input, C, hidden, W_ihT,
                     W_hhT, TQK, b_ih, b_hh, part, gi, gh, tvec);
  hipLaunchKernelGGL(k_mid, dim3(1024 + 1536), dim3(256), 0, stream, part,
                     tvec, S, scores, ST);
  hipLaunchKernelGGL(k_chain, dim3(B_), dim3(256), 0, stream, scores, part,
                     WvT, gi, gh, hidden, S, ST, h_new, cat, p_ptr);
  hipLaunchKernelGGL(k_pvocab, dim3(VOCAB_ / 128), dim3(128), 0, stream, cat,
                     W1_w, W1_b, p_vocab);
}

// Round 6
// 389.150 us; speedup vs baseline: 1.4413x; 1.0699x over previous
//
#include <hip/hip_runtime.h>
#include <hip/hip_bf16.h>
#include <math.h>

#define B_ 16
#define NT 64
#define LN 256
#define LV 4
#define D_ 256
#define VOCAB_ 32000
#define M_ 128
#define LS 4

typedef unsigned short ushort_t;
typedef unsigned int uint_t;

__device__ __forceinline__ ushort_t f2bf(float f) {
  uint_t u = __float_as_uint(f);
  uint_t r = u + 0x7FFFu + ((u >> 16) & 1u);
  return (ushort_t)(r >> 16);
}
__device__ __forceinline__ float bflo(uint_t u) {
  return __uint_as_float(u << 16);
}
__device__ __forceinline__ float bfhi(uint_t u) {
  return __uint_as_float(u & 0xFFFF0000u);
}

// ---------------- K_prep: S gather | C0->bf16 | W_ih^T | W_hh^T | TQK | WvT -
#define NB_S (3 * B_ * M_)  // 6144
#define NB_CONV 2048
#define NB_TR 192   // 768x256 -> 24x8 tiles of 32x32 (per weight)
#define NB_TQK 256
#define NB_WVT 64   // 256x256 -> 8x8 tiles
__global__ __launch_bounds__(256) void k_prep(
    const int* __restrict__ story, const float* __restrict__ C,
    const float* __restrict__ W_ih, const float* __restrict__ W_hh,
    const float* __restrict__ Wq, const float* __restrict__ Wk,
    const float* __restrict__ Wv, float* __restrict__ S,
    ushort_t* __restrict__ C0h, float* __restrict__ W_ihT,
    float* __restrict__ W_hhT, float* __restrict__ TQK,
    float* __restrict__ WvT) {
  __shared__ float smem[32 * 33];
  int blk = blockIdx.x, tid = threadIdx.x;
  if (blk < NB_S) {
    int h = blk / (B_ * M_);
    int bm = blk % (B_ * M_);
    const int* st = story + (size_t)bm * LS;
    const float* Ch = C + (size_t)h * VOCAB_ * D_;
    float s = Ch[(size_t)st[0] * D_ + tid] + Ch[(size_t)st[1] * D_ + tid] +
              Ch[(size_t)st[2] * D_ + tid] + Ch[(size_t)st[3] * D_ + tid];
    S[(size_t)blk * D_ + tid] = s;
  } else if (blk < NB_S + NB_CONV) {
    int n4 = VOCAB_ * D_ / 4;
    for (int i = (blk - NB_S) * 256 + tid; i < n4; i += NB_CONV * 256) {
      float4 f = ((const float4*)C)[i];
      uint2 packed;
      packed.x = (uint_t)f2bf(f.x) | ((uint_t)f2bf(f.y) << 16);
      packed.y = (uint_t)f2bf(f.z) | ((uint_t)f2bf(f.w) << 16);
      ((uint2*)C0h)[i] = packed;
    }
  } else if (blk < NB_S + NB_CONV + 2 * NB_TR) {
    int t = blk - (NB_S + NB_CONV);
    const float* W = W_ih;
    float* WT = W_ihT;
    if (t >= NB_TR) { t -= NB_TR; W = W_hh; WT = W_hhT; }
    const int R = 768;
    int tr = t % (R / 32), tc = t / (R / 32);
    int tx = tid & 31, ty = tid >> 5;
#pragma unroll
    for (int k = 0; k < 4; ++k)
      smem[(ty + 8 * k) * 33 + tx] =
          W[(size_t)(tr * 32 + ty + 8 * k) * D_ + tc * 32 + tx];
    __syncthreads();
#pragma unroll
    for (int k = 0; k < 4; ++k)
      WT[(size_t)(tc * 32 + ty + 8 * k) * R + tr * 32 + tx] =
          smem[tx * 33 + ty + 8 * k];
  } else if (blk < NB_S + NB_CONV + 2 * NB_TR + NB_TQK) {
    // TQK[j,i] = sum_k Wq[k,j] * Wk[k,i]
    int j = blk - (NB_S + NB_CONV + 2 * NB_TR);
    smem[tid] = Wq[(size_t)tid * D_ + j];
    __syncthreads();
    float acc = 0.f;
#pragma unroll 8
    for (int k = 0; k < D_; ++k) acc += smem[k] * Wk[(size_t)k * D_ + tid];
    TQK[(size_t)j * D_ + tid] = acc;
  } else {
    // WvT[j,r] = Wv[r,j]
    int t = blk - (NB_S + NB_CONV + 2 * NB_TR + NB_TQK);
    int tr = t & 7, tc = t >> 3;
    int tx = tid & 31, ty = tid >> 5;
#pragma unroll
    for (int k = 0; k < 4; ++k)
      smem[(ty + 8 * k) * 33 + tx] =
          Wv[(size_t)(tr * 32 + ty + 8 * k) * D_ + tc * 32 + tx];
    __syncthreads();
#pragma unroll
    for (int k = 0; k < 4; ++k)
      WvT[(size_t)(tc * 32 + ty + 8 * k) * D_ + tr * 32 + tx] =
          smem[tx * 33 + ty + 8 * k];
  }
}

// ---------------- K_rootsg: roots partials (wave-per-row) + gates + tvec ----
// LDS: 16 KB shared buffer, unioned between the gather branch (6.5 KB used)
// and the gates branch (16 KB xs) so gather blocks keep 10 blocks/CU.
__global__ __launch_bounds__(256) void k_rootsg(
    const int* __restrict__ kb_values, const int* __restrict__ kb_types,
    const ushort_t* __restrict__ C0h, const float* __restrict__ T_emb,
    const int* __restrict__ dec, const float* __restrict__ C0,
    const float* __restrict__ hidden, const float* __restrict__ W_ihT,
    const float* __restrict__ W_hhT, const float* __restrict__ TQK,
    const float* __restrict__ b_ih, const float* __restrict__ b_hh,
    float* __restrict__ part, float* __restrict__ gi, float* __restrict__ gh,
    float* __restrict__ tvec) {
  __shared__ __align__(16) char smem_raw[16384];
  int blk = blockIdx.x, tid = threadIdx.x;
  if (blk < 2048) {
    int bn = blk >> 1;
    int half = blk & 1;
    int lane = tid & 63, team = tid >> 6;
    int* sv = (int*)smem_raw;                    // 512 ints  (2 KB)
    int* st = (int*)(smem_raw + 2048);           // 128 ints  (0.5 KB)
    float* psum = (float*)(smem_raw + 2560);     // 4*256 fl  (4 KB)
    const int* vptr = kb_values + (size_t)bn * LN * LV + half * 128 * LV;
    for (int i = tid; i < 128 * LV; i += 256) sv[i] = vptr[i];
    if (tid < 128) st[tid] = kb_types[(size_t)bn * LN + half * 128 + tid];
    __syncthreads();
    // each lane owns columns 4*lane..4*lane+3; team handles 32 leaves
    float a0 = 0.f, a1 = 0.f, a2 = 0.f, a3 = 0.f;
#pragma unroll 4
    for (int li = 0; li < 32; ++li) {
      int l = team * 32 + li;
      int4 v = ((const int4*)sv)[l];
      uint2 u0 = ((const uint2*)(C0h + (size_t)v.x * D_))[lane];
      uint2 u1 = ((const uint2*)(C0h + (size_t)v.y * D_))[lane];
      uint2 u2 = ((const uint2*)(C0h + (size_t)v.z * D_))[lane];
      uint2 u3 = ((const uint2*)(C0h + (size_t)v.w * D_))[lane];
      float4 t4 = ((const float4*)(T_emb + (size_t)st[l] * D_))[lane];
      float s0 = bflo(u0.x) + bflo(u1.x) + bflo(u2.x) + bflo(u3.x);
      float s1 = bfhi(u0.x) + bfhi(u1.x) + bfhi(u2.x) + bfhi(u3.x);
      float s2 = bflo(u0.y) + bflo(u1.y) + bflo(u2.y) + bflo(u3.y);
      float s3 = bfhi(u0.y) + bfhi(u1.y) + bfhi(u2.y) + bfhi(u3.y);
      a0 += t4.x * s0;
      a1 += t4.y * s1;
      a2 += t4.z * s2;
      a3 += t4.w * s3;
    }
    psum[team * D_ + 4 * lane + 0] = a0;
    psum[team * D_ + 4 * lane + 1] = a1;
    psum[team * D_ + 4 * lane + 2] = a2;
    psum[team * D_ + 4 * lane + 3] = a3;
    __syncthreads();
    float r = psum[0 * D_ + tid] + psum[1 * D_ + tid] + psum[2 * D_ + tid] +
              psum[3 * D_ + tid];
    part[((size_t)bn * 2 + half) * D_ + tid] = r;
  } else {
    int g = blk - 2048;  // 0..2: gi, 3..5: gh, 6: tvec
    float* xs = (float*)smem_raw;  // [16][256] = 16 KB
    float acc[B_];
    if (g < 3) {
#pragma unroll
      for (int b = 0; b < B_; ++b)
        xs[b * D_ + tid] = C0[(size_t)dec[b] * D_ + tid];
      __syncthreads();
      int i = g * 256 + tid;
      float bias = b_ih[i];
#pragma unroll
      for (int b = 0; b < B_; ++b) acc[b] = bias;
#pragma unroll 4
      for (int j = 0; j < D_; ++j) {
        float w = W_ihT[(size_t)j * 768 + i];
#pragma unroll
        for (int b = 0; b < B_; ++b) acc[b] += xs[b * D_ + j] * w;
      }
#pragma unroll
      for (int b = 0; b < B_; ++b) gi[(size_t)b * 768 + i] = acc[b];
    } else if (g < 6) {
#pragma unroll
      for (int b = 0; b < B_; ++b) xs[b * D_ + tid] = hidden[b * D_ + tid];
      __syncthreads();
      int i = (g - 3) * 256 + tid;
      float bias = b_hh[i];
#pragma unroll
      for (int b = 0; b < B_; ++b) acc[b] = bias;
#pragma unroll 4
      for (int j = 0; j < D_; ++j) {
        float w = W_hhT[(size_t)j * 768 + i];
#pragma unroll
        for (int b = 0; b < B_; ++b) acc[b] += xs[b * D_ + j] * w;
      }
#pragma unroll
      for (int b = 0; b < B_; ++b) gh[(size_t)b * 768 + i] = acc[b];
    } else {
#pragma unroll
      for (int b = 0; b < B_; ++b) xs[b * D_ + tid] = hidden[b * D_ + tid];
      __syncthreads();
#pragma unroll
      for (int b = 0; b < B_; ++b) acc[b] = 0.f;
#pragma unroll 4
      for (int j = 0; j < D_; ++j) {
        float w = TQK[(size_t)j * D_ + tid];
#pragma unroll
        for (int b = 0; b < B_; ++b) acc[b] += xs[b * D_ + j] * w;
      }
#pragma unroll
      for (int b = 0; b < B_; ++b) tvec[b * D_ + tid] = acc[b];
    }
  }
}

// ---------------- K_mid: scores (1024 blocks) + S transpose (1536 blocks) ---
__global__ __launch_bounds__(256) void k_mid(
    const float* __restrict__ part, const float* __restrict__ tvec,
    const float* __restrict__ S, float* __restrict__ scores,
    float* __restrict__ ST) {
  int blk = blockIdx.x, tid = threadIdx.x;
  if (blk < 1024) {
    int b = blk >> 6;
    const float* p = part + (size_t)blk * 2 * D_;
    float rv = p[tid] + p[D_ + tid];
    float sc = rv * tvec[b * D_ + tid];
    float sm = rv;
    __shared__ float red[8];
    int lane = tid & 63, wave = tid >> 6;
    for (int o = 32; o > 0; o >>= 1) {
      sc += __shfl_xor(sc, o);
      sm += __shfl_xor(sm, o);
    }
    if (lane == 0) { red[wave] = sc; red[4 + wave] = sm; }
    __syncthreads();
    if (tid == 0) {
      float SC = red[0] + red[1] + red[2] + red[3];
      float SM = red[4] + red[5] + red[6] + red[7];
      scores[blk] = (SM == 0.0f) ? SC - 1000000000.0f : SC;
    }
  } else {
    // ST[hb][d][m] = S[hb][m][d]
    int t = blk - 1024;
    int hb = t >> 5;
    int tile = t & 31;
    int tm = tile & 3, td = tile >> 2;
    int tx = tid & 31, ty = tid >> 5;
    __shared__ float sm2[32 * 33];
    const float* Sp = S + (size_t)hb * M_ * D_;
    float* STp = ST + (size_t)hb * D_ * M_;
#pragma unroll
    for (int k = 0; k < 4; ++k)
      sm2[(ty + 8 * k) * 33 + tx] =
          Sp[(size_t)(tm * 32 + ty + 8 * k) * D_ + td * 32 + tx];
    __syncthreads();
#pragma unroll
    for (int k = 0; k < 4; ++k)
      STp[(size_t)(td * 32 + ty + 8 * k) * M_ + tm * 32 + tx] =
          sm2[tx * 33 + ty + 8 * k];
  }
}

// ---------------- K_chain: softmax/rbar/feat/GRU/hops (grid=16) -------------
__global__ __launch_bounds__(256) void k_chain(
    const float* __restrict__ scores, const float* __restrict__ part,
    const float* __restrict__ WvT, const float* __restrict__ gi,
    const float* __restrict__ gh, const float* __restrict__ hidden,
    const float* __restrict__ S, const float* __restrict__ ST,
    float* __restrict__ h_new_out, float* __restrict__ cat,
    float* __restrict__ p_ptr) {
  int b = blockIdx.x, tid = threadIdx.x;
  __shared__ float wsh[NT], rs[D_], us[D_], lo[M_], loB[M_], pr[M_];
  if (tid < NT) {
    float s = scores[b * NT + tid];
    float m = s;
    for (int o = 32; o > 0; o >>= 1) m = fmaxf(m, __shfl_xor(m, o));
    float e = expf(s - m);
    float sum = e;
    for (int o = 32; o > 0; o >>= 1) sum += __shfl_xor(sum, o);
    wsh[tid] = e / sum;
  }
  __syncthreads();
  float rb = 0.f;
#pragma unroll 16
  for (int n = 0; n < NT; ++n) {
    const float* p = part + ((size_t)(b * NT + n) * 2) * D_;
    rb += wsh[n] * (p[tid] + p[D_ + tid]);
  }
  rs[tid] = rb;
  __syncthreads();
  float feat = 0.f;
#pragma unroll 16
  for (int j = 0; j < D_; ++j) feat += rs[j] * WvT[(size_t)j * D_ + tid];
  {
    float i_r = gi[(size_t)b * 768 + tid];
    float i_z = gi[(size_t)b * 768 + 256 + tid];
    float i_n = gi[(size_t)b * 768 + 512 + tid];
    float h_r = gh[(size_t)b * 768 + tid];
    float h_z = gh[(size_t)b * 768 + 256 + tid];
    float h_n = gh[(size_t)b * 768 + 512 + tid];
    float h = hidden[b * D_ + tid];
    float r = 1.f / (1.f + expf(-(i_r + h_r)));
    float z = 1.f / (1.f + expf(-(i_z + h_z)));
    float nn = tanhf(i_n + r * h_n);
    float hn = (1.f - z) * nn + z * h;
    h_new_out[b * D_ + tid] = hn;
    float u0 = hn + feat;
    us[tid] = u0;
    cat[b * 512 + tid] = u0;
  }
  __syncthreads();
  for (int h = 0; h < 3; ++h) {
    {
      int m = tid & 127;
      int half = tid >> 7;
      const float* STp = ST + (((size_t)h * B_ + b) * D_ + half * 128) * M_;
      float l = 0.f;
#pragma unroll 16
      for (int d = 0; d < 128; ++d)
        l += us[half * 128 + d] * STp[(size_t)d * M_ + m];
      if (half == 0) lo[m] = l; else loB[m] = l;
    }
    __syncthreads();
    if (h == 2) {
      if (tid < M_) p_ptr[b * M_ + tid] = lo[tid] + loB[tid];
      break;
    }
    if (tid < 64) {
      float l0 = lo[tid] + loB[tid], l1 = lo[tid + 64] + loB[tid + 64];
      float a = fmaxf(l0, l1);
      for (int o = 32; o > 0; o >>= 1) a = fmaxf(a, __shfl_xor(a, o));
      float e0 = expf(l0 - a), e1 = expf(l1 - a);
      float s = e0 + e1;
      for (int o = 32; o > 0; o >>= 1) s += __shfl_xor(s, o);
      pr[tid] = e0 / s;
      pr[tid + 64] = e1 / s;
    }
    __syncthreads();
    {
      const float* Sn = S + (((size_t)(h + 1) * B_ + b) * M_) * D_;
      float o = 0.f;
#pragma unroll 16
      for (int m = 0; m < M_; ++m) o += pr[m] * Sn[(size_t)m * D_ + tid];
      if (h == 0) cat[b * 512 + D_ + tid] = o;
      us[tid] += o;
    }
    __syncthreads();
  }
}

// ---------------- K_pvocab: p_vocab = cat @ W1_w^T + b ----------------------
// grid=500, block=256: 64 vocab rows/block, 4-way K split, LDS reduce.
__global__ __launch_bounds__(256) void k_pvocab(
    const float* __restrict__ cat, const float* __restrict__ W1_w,
    const float* __restrict__ W1_b, float* __restrict__ out) {
  int blk = blockIdx.x, tid = threadIdx.x;
  int row = tid & 63, q = tid >> 6;  // q in 0..3 (k quarter)
  int v = blk * 64 + row;
  __shared__ float cs[B_ * 512];
  __shared__ float ps[3][64][B_];  // quarters 1..3 partials (12 KB)
  for (int i = tid; i < B_ * 512; i += 256) cs[i] = cat[i];
  __syncthreads();
  const float4* wrow = (const float4*)(W1_w + (size_t)v * 512 + q * 128);
  float acc[B_];
#pragma unroll
  for (int b = 0; b < B_; ++b) acc[b] = 0.f;
#pragma unroll 4
  for (int k4 = 0; k4 < 32; ++k4) {
    float4 w = wrow[k4];
#pragma unroll
    for (int b = 0; b < B_; ++b) {
      const float* c = &cs[b * 512 + q * 128 + k4 * 4];
      acc[b] += w.x * c[0] + w.y * c[1] + w.z * c[2] + w.w * c[3];
    }
  }
  if (q > 0) {
#pragma unroll
    for (int b = 0; b < B_; ++b) ps[q - 1][row][b] = acc[b];
  }
  __syncthreads();
  if (q == 0) {
    float bb = W1_b[v];
#pragma unroll
    for (int b = 0; b < B_; ++b)
      out[(size_t)b * VOCAB_ + v] =
          acc[b] + ps[0][row][b] + ps[1][row][b] + ps[2][row][b] + bb;
  }
}

extern "C" void kernel_launch(void* const* d_in, const int* in_sizes, int n_in,
                              void* d_out, int out_size, void* d_ws,
                              size_t ws_size, hipStream_t stream) {
  const int* decoder_input = (const int*)d_in[0];
  const int* story = (const int*)d_in[1];
  const float* hidden = (const float*)d_in[2];
  const int* kb_values = (const int*)d_in[3];
  const int* kb_types = (const int*)d_in[4];
  const float* C = (const float*)d_in[7];
  const float* T_emb = (const float*)d_in[8];
  const float* Wq = (const float*)d_in[9];
  const float* Wk = (const float*)d_in[10];
  const float* Wv = (const float*)d_in[11];
  const float* W1_w = (const float*)d_in[12];
  const float* W1_b = (const float*)d_in[13];
  const float* W_ih = (const float*)d_in[14];
  const float* W_hh = (const float*)d_in[15];
  const float* b_ih = (const float*)d_in[16];
  const float* b_hh = (const float*)d_in[17];

  float* out = (float*)d_out;
  float* p_ptr = out;                          // (16,128)
  float* p_vocab = out + B_ * M_;              // (16,32000)
  float* h_new = out + B_ * M_ + B_ * VOCAB_;  // (16,256)

  // workspace layout (floats). ST aliases W_ihT/W_hhT/TQK (dead by then).
  float* ws = (float*)d_ws;
  float* S = ws;                          // 1,572,864
  float* part = S + 3 * B_ * M_ * D_;     //   524,288
  float* cat = part + B_ * NT * 2 * D_;   //     8,192
  float* scores = cat + B_ * 512;         //     1,024
  float* gi = scores + B_ * NT;           //    12,288
  float* gh = gi + B_ * 768;              //    12,288
  float* tvec = gh + B_ * 768;            //     4,096
  ushort_t* C0h = (ushort_t*)(tvec + B_ * D_);   // 8,192,000 ushorts
  float* wtmp = (float*)(C0h + (size_t)VOCAB_ * D_);
  float* W_ihT = wtmp;                    //   196,608
  float* W_hhT = W_ihT + 768 * D_;        //   196,608
  float* TQK = W_hhT + 768 * D_;          //    65,536
  float* ST = wtmp;                       // alias: 1,572,864
  float* WvT = wtmp + 3 * B_ * M_ * D_;   //    65,536 (after ST region)

  hipLaunchKernelGGL(k_prep,
                     dim3(NB_S + NB_CONV + 2 * NB_TR + NB_TQK + NB_WVT),
                     dim3(256), 0, stream, story, C, W_ih, W_hh, Wq, Wk, Wv, S,
                     C0h, W_ihT, W_hhT, TQK, WvT);
  hipLaunchKernelGGL(k_rootsg, dim3(2048 + 7), dim3(256), 0, stream, kb_values,
                     kb_types, C0h, T_emb, decoder_input, C, hidden, W_ihT,
                     W_hhT, TQK, b_ih, b_hh, part, gi, gh, tvec);
  hipLaunchKernelGGL(k_mid, dim3(1024 + 1536), dim3(256), 0, stream, part,
                     tvec, S, scores, ST);
  hipLaunchKernelGGL(k_chain, dim3(B_), dim3(256), 0, stream, scores, part,
                     WvT, gi, gh, hidden, S, ST, h_new, cat, p_ptr);
  hipLaunchKernelGGL(k_pvocab, dim3(VOCAB_ / 64), dim3(256), 0, stream, cat,
                     W1_w, W1_b, p_vocab);
}